// Round 2
// baseline (35826.102 us; speedup 1.0000x reference)
//
#include <hip/hip_runtime.h>
#include <hip/hip_bf16.h>

// Model: BiLSTM (B*U=1024 seqs, W=32 steps, E=300, H=512) -> attention GRU decoder
// (U=64 sequential steps, B=16) -> linear classifier (C=7).
//
// Phase B (LSTM): per-step GEMM M=2048 (fwd 1024 + bwd 1024), N=2048 (4H gates),
//   K=832 (E=300 + H=512 padded), bf16 MFMA 16x16x32, fp32 accum.
// Phase C (decoder): fp32 skinny kernels, 5 dispatches/step.

#define DEV static __device__ __forceinline__

typedef __attribute__((ext_vector_type(4))) float f32x4;
typedef __attribute__((ext_vector_type(8))) short bf16x8;
typedef __attribute__((ext_vector_type(4))) unsigned short u16x4;

DEV float sigmoidf_(float x) { return 1.0f / (1.0f + __expf(-x)); }

DEV unsigned short f2bf(float f) {
    union { float f; unsigned u; } v; v.f = f;
    unsigned r = v.u + 0x7FFFu + ((v.u >> 16) & 1u);
    return (unsigned short)(r >> 16);
}

// ---------------- conversions ----------------

__global__ __launch_bounds__(256) void k_f2bf(const float* __restrict__ in,
                                              unsigned short* __restrict__ out, int n) {
    int idx = (blockIdx.x * 256 + threadIdx.x) * 4;
    if (idx + 3 >= n + 3) return;
    if (idx + 3 < n) {
        f32x4 v = *(const f32x4*)&in[idx];
        u16x4 o;
        o[0] = f2bf(v[0]); o[1] = f2bf(v[1]); o[2] = f2bf(v[2]); o[3] = f2bf(v[3]);
        *(u16x4*)&out[idx] = o;
    } else {
        for (int j = 0; j < 4 && idx + j < n; ++j) out[idx + j] = f2bf(in[idx + j]);
    }
}

// Wcat[dir][j][k]: k<300 -> Wih[j][k]; 300<=k<812 -> Whh[j][k-300]; else 0.  (2,2048,832) bf16
__global__ __launch_bounds__(256) void k_build_wcat(
    const float* __restrict__ wihf, const float* __restrict__ whhf,
    const float* __restrict__ wihb, const float* __restrict__ whhb,
    unsigned short* __restrict__ wcat) {
    int gt = blockIdx.x * 256 + threadIdx.x;
    if (gt >= 2 * 2048 * 832) return;
    int k = gt % 832;
    int j = (gt / 832) & 2047;
    int dir = gt / (832 * 2048);
    const float* wih = dir ? wihb : wihf;
    const float* whh = dir ? whhb : whhf;
    float v = 0.0f;
    if (k < 300) v = wih[j * 300 + k];
    else if (k < 812) v = whh[j * 512 + (k - 300)];
    wcat[gt] = f2bf(v);
}

// ---------------- Phase B: LSTM step GEMM (bf16 MFMA) ----------------
// gates[dir][n][j] = sum_k A[n][k] * Wcat[dir][j][k]
// A[n][k] = k<300 ? x_bf[n][t_eff][k] : (k<812 ? h_bf[dir][n][k-300] : 0)

__global__ __launch_bounds__(256) void k_lstm_gemm(
    const unsigned short* __restrict__ xbf,   // (1024,32,300)
    const unsigned short* __restrict__ hbff,  // (1024,512)
    const unsigned short* __restrict__ hbfb,  // (1024,512)
    const unsigned short* __restrict__ wcat,  // (2,2048,832)
    float* __restrict__ gates,                // (2,1024,2048)
    int t) {
    __shared__ unsigned short As[64][72];
    __shared__ unsigned short Ws[64][72];

    const int tid  = threadIdx.x;
    const int br   = blockIdx.x;       // 0..31 M-tiles (2048 rows)
    const int bc   = blockIdx.y;       // 0..31 N-tiles
    const int row0 = br * 64;
    const int dir  = row0 >> 10;
    const int n0   = row0 & 1023;
    const int col0 = bc * 64;
    const int teff = dir ? (31 - t) : t;
    const unsigned short* hbf = dir ? hbfb : hbff;
    const unsigned short* wb  = wcat + (size_t)dir * 2048 * 832;

    const int lane = tid & 63;
    const int wv   = tid >> 6;
    const int wm   = (wv >> 1) * 32;
    const int wn   = (wv & 1) * 32;
    const int srow = tid >> 2;            // 0..63 staging row
    const int sk0  = (tid & 3) * 16;      // 16 k per thread
    const int arow = lane & 15;
    const int kq   = (lane >> 4) * 8;

    f32x4 acc[2][2];
#pragma unroll
    for (int i = 0; i < 2; ++i)
#pragma unroll
        for (int j = 0; j < 2; ++j) acc[i][j] = (f32x4){0.f, 0.f, 0.f, 0.f};

    const int nrow = n0 + srow;
    const int wrow = col0 + srow;
    const unsigned short* xrow = xbf + ((size_t)nrow * 32 + teff) * 300;
    const unsigned short* hrow = hbf + (size_t)nrow * 512;
    const unsigned short* wrp  = wb + (size_t)wrow * 832;

    for (int kt = 0; kt < 13; ++kt) {
        const int kb = kt * 64 + sk0;
#pragma unroll
        for (int e = 0; e < 16; ++e) {
            int k = kb + e;
            unsigned short v;
            if (k < 300) v = xrow[k];
            else if (k < 812) v = hrow[k - 300];
            else v = 0;
            As[srow][sk0 + e] = v;
            Ws[srow][sk0 + e] = wrp[k];
        }
        __syncthreads();
#pragma unroll
        for (int kk = 0; kk < 64; kk += 32) {
            bf16x8 af[2], bfg[2];
#pragma unroll
            for (int i = 0; i < 2; ++i) {
                af[i]  = *(const bf16x8*)&As[wm + i * 16 + arow][kk + kq];
                bfg[i] = *(const bf16x8*)&Ws[wn + i * 16 + arow][kk + kq];
            }
#pragma unroll
            for (int i = 0; i < 2; ++i)
#pragma unroll
                for (int j = 0; j < 2; ++j)
                    acc[i][j] = __builtin_amdgcn_mfma_f32_16x16x32_bf16(
                        af[i], bfg[j], acc[i][j], 0, 0, 0);
        }
        __syncthreads();
    }

    const int rrow = (lane >> 4) * 4;
    const int ccol = lane & 15;
    float* gout = gates + (size_t)dir * 1024 * 2048;
#pragma unroll
    for (int i = 0; i < 2; ++i)
#pragma unroll
        for (int j = 0; j < 2; ++j) {
            int nrw = n0 + wm + i * 16 + rrow;
            int cl  = col0 + wn + j * 16 + ccol;
#pragma unroll
            for (int r = 0; r < 4; ++r)
                gout[(size_t)(nrw + r) * 2048 + cl] = acc[i][j][r];
        }
}

// LSTM pointwise: gate order i,f,g,o (chunks of 512)
__global__ __launch_bounds__(256) void k_lstm_point(
    const float* __restrict__ gates, float* __restrict__ c, float* __restrict__ h,
    unsigned short* __restrict__ hbf,
    const float* __restrict__ bihf, const float* __restrict__ bhhf,
    const float* __restrict__ bihb, const float* __restrict__ bhhb) {
    int gt = blockIdx.x * 256 + threadIdx.x;   // 2*1024*512
    int j   = gt & 511;
    int n   = (gt >> 9) & 1023;
    int dir = gt >> 19;
    const float* g   = gates + (size_t)dir * 1024 * 2048 + (size_t)n * 2048;
    const float* bih = dir ? bihb : bihf;
    const float* bhh = dir ? bhhb : bhhf;
    float iv = g[j]        + bih[j]        + bhh[j];
    float fv = g[j + 512]  + bih[j + 512]  + bhh[j + 512];
    float gv = g[j + 1024] + bih[j + 1024] + bhh[j + 1024];
    float ov = g[j + 1536] + bih[j + 1536] + bhh[j + 1536];
    size_t idx = (size_t)dir * 524288 + (size_t)n * 512 + j;
    float cv = sigmoidf_(fv) * c[idx] + sigmoidf_(iv) * tanhf(gv);
    float hv = sigmoidf_(ov) * tanhf(cv);
    c[idx] = cv;
    h[idx] = hv;
    hbf[idx] = f2bf(hv);
}

// feat[n][d] = d<512 ? h_f[n][d] : h_b[n][d-512]
__global__ __launch_bounds__(256) void k_feat(const float* __restrict__ h,
                                              float* __restrict__ feat) {
    int idx = blockIdx.x * 256 + threadIdx.x;   // 1024*1024
    int n = idx >> 10;
    int d = idx & 1023;
    feat[idx] = (d < 512) ? h[(size_t)n * 512 + d]
                          : h[524288 + (size_t)n * 512 + (d - 512)];
}

// ---------------- Phase C: decoder ----------------

// GRU cell, M=16 rows. x = xa (+ xb), h. out[m][d].
__global__ __launch_bounds__(256) void k_gru(
    const float* __restrict__ xa, long xaStride, const float* __restrict__ xb,
    const float* __restrict__ h, int hStride,
    const float* __restrict__ Wih, const float* __restrict__ Whh,
    const float* __restrict__ bih, const float* __restrict__ bhh,
    float* __restrict__ out, int outStride,
    int Dout, int Kx, int Kh) {
    int gt = blockIdx.x * 256 + threadIdx.x;
    int m = gt & 15;
    int d = gt >> 4;
    if (d >= Dout) return;
    const float* wr = Wih + (size_t)d * Kx;
    const float* wz = wr + (size_t)Dout * Kx;
    const float* wn = wz + (size_t)Dout * Kx;
    const float* xr  = xa + (size_t)m * xaStride;
    const float* xbr = xb ? xb + (size_t)m * Kx : (const float*)0;
    float ir = 0.f, iz = 0.f, inn = 0.f;
    for (int k = 0; k < Kx; k += 4) {
        f32x4 xv = *(const f32x4*)&xr[k];
        if (xbr) { f32x4 tv = *(const f32x4*)&xbr[k]; xv = xv + tv; }
        f32x4 a = *(const f32x4*)&wr[k];
        f32x4 b = *(const f32x4*)&wz[k];
        f32x4 cc = *(const f32x4*)&wn[k];
        ir  += xv[0]*a[0]  + xv[1]*a[1]  + xv[2]*a[2]  + xv[3]*a[3];
        iz  += xv[0]*b[0]  + xv[1]*b[1]  + xv[2]*b[2]  + xv[3]*b[3];
        inn += xv[0]*cc[0] + xv[1]*cc[1] + xv[2]*cc[2] + xv[3]*cc[3];
    }
    const float* vr = Whh + (size_t)d * Kh;
    const float* vz = vr + (size_t)Dout * Kh;
    const float* vn = vz + (size_t)Dout * Kh;
    const float* hrow = h + (size_t)m * hStride;
    float hr = 0.f, hz = 0.f, hn = 0.f;
    for (int k = 0; k < Kh; k += 4) {
        f32x4 hv = *(const f32x4*)&hrow[k];
        f32x4 a = *(const f32x4*)&vr[k];
        f32x4 b = *(const f32x4*)&vz[k];
        f32x4 cc = *(const f32x4*)&vn[k];
        hr += hv[0]*a[0]  + hv[1]*a[1]  + hv[2]*a[2]  + hv[3]*a[3];
        hz += hv[0]*b[0]  + hv[1]*b[1]  + hv[2]*b[2]  + hv[3]*b[3];
        hn += hv[0]*cc[0] + hv[1]*cc[1] + hv[2]*cc[2] + hv[3]*cc[3];
    }
    float r = sigmoidf_(ir + bih[d] + hr + bhh[d]);
    float z = sigmoidf_(iz + bih[d + Dout] + hz + bhh[d + Dout]);
    float nn = tanhf(inn + bih[d + 2 * Dout] + r * (hn + bhh[d + 2 * Dout]));
    float hp = hrow[d];
    out[(size_t)m * outStride + d] = (1.0f - z) * nn + z * hp;
}

// q[m][d] = sum_k u[m][k] * Wg[k][d]   (u row m = feat[(m*64+i)*1024])
__global__ __launch_bounds__(256) void k_qproj(const float* __restrict__ feat,
                                               const float* __restrict__ Wg,
                                               float* __restrict__ q, int i) {
    int gt = blockIdx.x * 256 + threadIdx.x;  // 16384
    int d = gt & 1023;
    int m = gt >> 10;
    const float* u = feat + ((size_t)m * 64 + i) * 1024;
    float s = 0.f;
    for (int k = 0; k < 1024; ++k) s += u[k] * Wg[(size_t)k * 1024 + d];
    q[(size_t)m * 1024 + d] = s;
}

// attention: scores over hist[0..i], softmax, ctx. grid = 64 blocks: b=blk>>2, part=blk&3.
__global__ __launch_bounds__(256) void k_attn(const float* __restrict__ q,
                                              const float* __restrict__ hist,
                                              float* __restrict__ ctxout, int i) {
    __shared__ float sc[66];
    int b = blockIdx.x >> 2;
    int part = blockIdx.x & 3;
    int tid = threadIdx.x;
    int lane = tid & 63;
    int wv = tid >> 6;
    const float* qb = q + (size_t)b * 1024;
    for (int t = wv; t <= i; t += 4) {
        const float* hrow = hist + ((size_t)t * 16 + b) * 1024;
        float s = 0.f;
        for (int d = lane; d < 1024; d += 64) s += qb[d] * hrow[d];
        for (int o = 32; o > 0; o >>= 1) s += __shfl_down(s, o);
        if (lane == 0) sc[t] = s;
    }
    __syncthreads();
    if (tid == 0) {
        float mx = -1e30f;
        for (int t = 0; t <= i; ++t) mx = fmaxf(mx, sc[t]);
        float sum = 0.f;
        for (int t = 0; t <= i; ++t) { float e = __expf(sc[t] - mx); sc[t] = e; sum += e; }
        sc[65] = 1.0f / sum;
    }
    __syncthreads();
    float inv = sc[65];
    int d = part * 256 + tid;
    float s = 0.f;
    for (int t = 0; t <= i; ++t) s += sc[t] * hist[((size_t)t * 16 + b) * 1024 + d];
    ctxout[(size_t)b * 1024 + d] = s * inv;
}

// out[b][u][c] = dot(es[u][b], cls_W[c]) + cls_b[c]
__global__ __launch_bounds__(256) void k_cls(const float* __restrict__ es,
                                             const float* __restrict__ W,
                                             const float* __restrict__ bias,
                                             float* __restrict__ out) {
    int blk = blockIdx.x;  // 1024 = b*64+u
    int b = blk >> 6;
    int u = blk & 63;
    const float* erow = es + ((size_t)u * 16 + b) * 512;
    int tid = threadIdx.x;
    int lane = tid & 63;
    int wv = tid >> 6;
    for (int c = wv; c < 7; c += 4) {
        float s = 0.f;
        for (int k = lane; k < 512; k += 64) s += erow[k] * W[(size_t)c * 512 + k];
        for (int o = 32; o > 0; o >>= 1) s += __shfl_down(s, o);
        if (lane == 0) out[((size_t)b * 64 + u) * 7 + c] = s + bias[c];
    }
}

// ---------------- host ----------------

extern "C" void kernel_launch(void* const* d_in, const int* in_sizes, int n_in,
                              void* d_out, int out_size, void* d_ws, size_t ws_size,
                              hipStream_t stream) {
    (void)in_sizes; (void)n_in; (void)out_size; (void)ws_size;
    const float* x          = (const float*)d_in[0];
    const float* lstm_Wih_f = (const float*)d_in[1];
    const float* lstm_Whh_f = (const float*)d_in[2];
    const float* lstm_bih_f = (const float*)d_in[3];
    const float* lstm_bhh_f = (const float*)d_in[4];
    const float* lstm_Wih_b = (const float*)d_in[5];
    const float* lstm_Whh_b = (const float*)d_in[6];
    const float* lstm_bih_b = (const float*)d_in[7];
    const float* lstm_bhh_b = (const float*)d_in[8];
    const float* gg_Wih = (const float*)d_in[9];
    const float* gg_Whh = (const float*)d_in[10];
    const float* gg_bih = (const float*)d_in[11];
    const float* gg_bhh = (const float*)d_in[12];
    const float* Wg     = (const float*)d_in[13];
    const float* pg_Wih = (const float*)d_in[14];
    const float* pg_Whh = (const float*)d_in[15];
    const float* pg_bih = (const float*)d_in[16];
    const float* pg_bhh = (const float*)d_in[17];
    const float* eg_Wih = (const float*)d_in[18];
    const float* eg_Whh = (const float*)d_in[19];
    const float* eg_bih = (const float*)d_in[20];
    const float* eg_bhh = (const float*)d_in[21];
    const float* cls_W  = (const float*)d_in[22];
    const float* cls_b  = (const float*)d_in[23];

    char* wsp = (char*)d_ws;
    size_t off = 0;
    auto alloc = [&](size_t bytes) -> void* {
        void* p = wsp + off;
        off += (bytes + 255) & ~(size_t)255;
        return p;
    };
    unsigned short* x_bf = (unsigned short*)alloc((size_t)9830400 * 2);
    unsigned short* wcat = (unsigned short*)alloc((size_t)2 * 2048 * 832 * 2);
    unsigned short* hbf  = (unsigned short*)alloc((size_t)2 * 1024 * 512 * 2);
    float* hbuf  = (float*)alloc((size_t)2 * 1024 * 512 * 4);
    float* cbuf  = (float*)alloc((size_t)2 * 1024 * 512 * 4);
    float* gates = (float*)alloc((size_t)2 * 1024 * 2048 * 4);
    float* feat  = (float*)alloc((size_t)1024 * 1024 * 4);
    float* hist  = (float*)alloc((size_t)65 * 16 * 1024 * 4);
    float* qbuf  = (float*)alloc((size_t)16 * 1024 * 4);
    float* ctxb  = (float*)alloc((size_t)16 * 1024 * 4);
    float* pnew  = (float*)alloc((size_t)64 * 16 * 1024 * 4);
    float* esb   = (float*)alloc((size_t)64 * 16 * 512 * 4);
    float* zeroD = (float*)alloc((size_t)16 * 1024 * 4);
    float* zeroH = (float*)alloc((size_t)16 * 512 * 4);

    hipMemsetAsync(hbf, 0, (size_t)2 * 1024 * 512 * 2, stream);
    hipMemsetAsync(cbuf, 0, (size_t)2 * 1024 * 512 * 4, stream);
    hipMemsetAsync(hist, 0, (size_t)65 * 16 * 1024 * 4, stream);
    hipMemsetAsync(zeroD, 0, (size_t)16 * 1024 * 4, stream);
    hipMemsetAsync(zeroH, 0, (size_t)16 * 512 * 4, stream);

    k_f2bf<<<9600, 256, 0, stream>>>(x, x_bf, 9830400);
    k_build_wcat<<<13312, 256, 0, stream>>>(lstm_Wih_f, lstm_Whh_f, lstm_Wih_b, lstm_Whh_b, wcat);

    for (int t = 0; t < 32; ++t) {
        k_lstm_gemm<<<dim3(32, 32), 256, 0, stream>>>(x_bf, hbf, hbf + 524288, wcat, gates, t);
        k_lstm_point<<<4096, 256, 0, stream>>>(gates, cbuf, hbuf, hbf,
                                               lstm_bih_f, lstm_bhh_f, lstm_bih_b, lstm_bhh_b);
    }
    k_feat<<<4096, 256, 0, stream>>>(hbuf, feat);

    float* p0 = zeroD;
    float* p1 = zeroD;
    for (int i = 0; i < 64; ++i) {
        float* psel = (i & 1) ? p1 : p0;
        // gg GRU: x = u + p, h = hist[i] -> hist[i+1]
        k_gru<<<64, 256, 0, stream>>>(feat + (size_t)i * 1024, 65536L, psel,
                                      hist + (size_t)i * 16384, 1024,
                                      gg_Wih, gg_Whh, gg_bih, gg_bhh,
                                      hist + (size_t)(i + 1) * 16384, 1024,
                                      1024, 1024, 1024);
        k_qproj<<<64, 256, 0, stream>>>(feat, Wg, qbuf, i);
        k_attn<<<64, 256, 0, stream>>>(qbuf, hist, ctxb, i);
        float* pn = pnew + (size_t)i * 16384;
        // pg GRU: x = u + ctx, h = p -> pnew
        k_gru<<<64, 256, 0, stream>>>(feat + (size_t)i * 1024, 65536L, ctxb,
                                      psel, 1024,
                                      pg_Wih, pg_Whh, pg_bih, pg_bhh,
                                      pn, 1024,
                                      1024, 1024, 1024);
        if (i & 1) p1 = pn; else p0 = pn;
        const float* eprev = (i == 0) ? zeroH : (esb + (size_t)(i - 1) * 8192);
        // eg GRU: x = p_new (K=1024), h = e (K=512) -> es[i]
        k_gru<<<32, 256, 0, stream>>>(pn, 1024L, (const float*)0,
                                      eprev, 512,
                                      eg_Wih, eg_Whh, eg_bih, eg_bhh,
                                      esb + (size_t)i * 8192, 512,
                                      512, 1024, 512);
    }
    k_cls<<<1024, 256, 0, stream>>>(esb, cls_W, cls_b, (float*)d_out);
}

// Round 3
// 11963.141 us; speedup vs baseline: 2.9947x; 2.9947x over previous
//
#include <hip/hip_runtime.h>
#include <hip/hip_bf16.h>

// Model: BiLSTM (B*U=1024 seqs, W=32 steps, E=300, H=512) -> attention GRU decoder
// (U=64 sequential steps, B=16) -> linear classifier (C=7).
//
// Phase B (LSTM): per-step GEMM M=2048, N=2048, K=832, bf16 MFMA 16x16x32.
// Phase C (decoder): fused bf16-MFMA GRU kernels (GEMM + gate math, 1 launch each),
//   q-projection hoisted out of the loop as one big GEMM.

#define DEV static __device__ __forceinline__

typedef __attribute__((ext_vector_type(4))) float f32x4;
typedef __attribute__((ext_vector_type(8))) short bf16x8;
typedef __attribute__((ext_vector_type(4))) unsigned short u16x4;
typedef __attribute__((ext_vector_type(8))) unsigned short u16x8;

DEV float sigmoidf_(float x) { return 1.0f / (1.0f + __expf(-x)); }

DEV unsigned short f2bf(float f) {
    union { float f; unsigned u; } v; v.f = f;
    unsigned r = v.u + 0x7FFFu + ((v.u >> 16) & 1u);
    return (unsigned short)(r >> 16);
}

DEV bf16x8 cvt8(f32x4 a, f32x4 b) {
    bf16x8 r;
    r[0] = (short)f2bf(a[0]); r[1] = (short)f2bf(a[1]);
    r[2] = (short)f2bf(a[2]); r[3] = (short)f2bf(a[3]);
    r[4] = (short)f2bf(b[0]); r[5] = (short)f2bf(b[1]);
    r[6] = (short)f2bf(b[2]); r[7] = (short)f2bf(b[3]);
    return r;
}

// ---------------- conversions / packing ----------------

__global__ __launch_bounds__(256) void k_f2bf(const float* __restrict__ in,
                                              unsigned short* __restrict__ out, int n) {
    int idx = (blockIdx.x * 256 + threadIdx.x) * 4;
    if (idx + 3 >= n + 3) return;
    if (idx + 3 < n) {
        f32x4 v = *(const f32x4*)&in[idx];
        u16x4 o;
        o[0] = f2bf(v[0]); o[1] = f2bf(v[1]); o[2] = f2bf(v[2]); o[3] = f2bf(v[3]);
        *(u16x4*)&out[idx] = o;
    } else {
        for (int j = 0; j < 4 && idx + j < n; ++j) out[idx + j] = f2bf(in[idx + j]);
    }
}

// Wcat[dir][j][k]: k<300 -> Wih[j][k]; 300<=k<812 -> Whh[j][k-300]; else 0.  (2,2048,832) bf16
__global__ __launch_bounds__(256) void k_build_wcat(
    const float* __restrict__ wihf, const float* __restrict__ whhf,
    const float* __restrict__ wihb, const float* __restrict__ whhb,
    unsigned short* __restrict__ wcat) {
    int gt = blockIdx.x * 256 + threadIdx.x;
    if (gt >= 2 * 2048 * 832) return;
    int k = gt % 832;
    int j = (gt / 832) & 2047;
    int dir = gt / (832 * 2048);
    const float* wih = dir ? wihb : wihf;
    const float* whh = dir ? whhb : whhf;
    float v = 0.0f;
    if (k < 300) v = wih[j * 300 + k];
    else if (k < 812) v = whh[j * 512 + (k - 300)];
    wcat[gt] = f2bf(v);
}

// out[j][k] (rows x (K1+K2)) bf16: k<K1 -> Wih[j][k], else Whh[j][k-K1]. grid = rows.
__global__ __launch_bounds__(256) void k_cat_w(const float* __restrict__ Wih,
                                               const float* __restrict__ Whh,
                                               unsigned short* __restrict__ out,
                                               int K1, int K2) {
    int j = blockIdx.x;
    int KW = K1 + K2;
    const float* a = Wih + (size_t)j * K1;
    const float* b = Whh + (size_t)j * K2;
    unsigned short* o = out + (size_t)j * KW;
    for (int k = threadIdx.x; k < KW; k += 256)
        o[k] = f2bf(k < K1 ? a[k] : b[k - K1]);
}

// WgT[d][k] = bf16(Wg[k][d]), 1024x1024. grid (16,16), 256 threads.
__global__ __launch_bounds__(256) void k_transpose_bf(const float* __restrict__ in,
                                                      unsigned short* __restrict__ out) {
    __shared__ float t[64][65];
    int tid = threadIdx.x;
    int r0 = blockIdx.y * 64, c0 = blockIdx.x * 64;
#pragma unroll
    for (int rep = 0; rep < 16; ++rep) {
        int lin = rep * 256 + tid;
        int r = lin >> 6, c = lin & 63;
        t[r][c] = in[(size_t)(r0 + r) * 1024 + c0 + c];
    }
    __syncthreads();
#pragma unroll
    for (int rep = 0; rep < 16; ++rep) {
        int lin = rep * 256 + tid;
        int d = lin >> 6, k = lin & 63;
        out[(size_t)(c0 + d) * 1024 + r0 + k] = f2bf(t[k][d]);
    }
}

// ---------------- Phase B: LSTM step GEMM (bf16 MFMA) ----------------

__global__ __launch_bounds__(256) void k_lstm_gemm(
    const unsigned short* __restrict__ xbf,   // (1024,32,300)
    const unsigned short* __restrict__ hbff,  // (1024,512)
    const unsigned short* __restrict__ hbfb,  // (1024,512)
    const unsigned short* __restrict__ wcat,  // (2,2048,832)
    float* __restrict__ gates,                // (2,1024,2048)
    int t) {
    __shared__ unsigned short As[64][72];
    __shared__ unsigned short Ws[64][72];

    const int tid  = threadIdx.x;
    const int br   = blockIdx.x;
    const int bc   = blockIdx.y;
    const int row0 = br * 64;
    const int dir  = row0 >> 10;
    const int n0   = row0 & 1023;
    const int col0 = bc * 64;
    const int teff = dir ? (31 - t) : t;
    const unsigned short* hbf = dir ? hbfb : hbff;
    const unsigned short* wb  = wcat + (size_t)dir * 2048 * 832;

    const int lane = tid & 63;
    const int wv   = tid >> 6;
    const int wm   = (wv >> 1) * 32;
    const int wn   = (wv & 1) * 32;
    const int srow = tid >> 2;
    const int sk0  = (tid & 3) * 16;
    const int arow = lane & 15;
    const int kq   = (lane >> 4) * 8;

    f32x4 acc[2][2];
#pragma unroll
    for (int i = 0; i < 2; ++i)
#pragma unroll
        for (int j = 0; j < 2; ++j) acc[i][j] = (f32x4){0.f, 0.f, 0.f, 0.f};

    const int nrow = n0 + srow;
    const int wrow = col0 + srow;
    const unsigned short* xrow = xbf + ((size_t)nrow * 32 + teff) * 300;
    const unsigned short* hrow = hbf + (size_t)nrow * 512;
    const unsigned short* wrp  = wb + (size_t)wrow * 832;

    for (int kt = 0; kt < 13; ++kt) {
        const int kb = kt * 64 + sk0;
#pragma unroll
        for (int e = 0; e < 16; ++e) {
            int k = kb + e;
            unsigned short v;
            if (k < 300) v = xrow[k];
            else if (k < 812) v = hrow[k - 300];
            else v = 0;
            As[srow][sk0 + e] = v;
            Ws[srow][sk0 + e] = wrp[k];
        }
        __syncthreads();
#pragma unroll
        for (int kk = 0; kk < 64; kk += 32) {
            bf16x8 af[2], bfg[2];
#pragma unroll
            for (int i = 0; i < 2; ++i) {
                af[i]  = *(const bf16x8*)&As[wm + i * 16 + arow][kk + kq];
                bfg[i] = *(const bf16x8*)&Ws[wn + i * 16 + arow][kk + kq];
            }
#pragma unroll
            for (int i = 0; i < 2; ++i)
#pragma unroll
                for (int j = 0; j < 2; ++j)
                    acc[i][j] = __builtin_amdgcn_mfma_f32_16x16x32_bf16(
                        af[i], bfg[j], acc[i][j], 0, 0, 0);
        }
        __syncthreads();
    }

    const int rrow = (lane >> 4) * 4;
    const int ccol = lane & 15;
    float* gout = gates + (size_t)dir * 1024 * 2048;
#pragma unroll
    for (int i = 0; i < 2; ++i)
#pragma unroll
        for (int j = 0; j < 2; ++j) {
            int nrw = n0 + wm + i * 16 + rrow;
            int cl  = col0 + wn + j * 16 + ccol;
#pragma unroll
            for (int r = 0; r < 4; ++r)
                gout[(size_t)(nrw + r) * 2048 + cl] = acc[i][j][r];
        }
}

__global__ __launch_bounds__(256) void k_lstm_point(
    const float* __restrict__ gates, float* __restrict__ c, float* __restrict__ h,
    unsigned short* __restrict__ hbf,
    const float* __restrict__ bihf, const float* __restrict__ bhhf,
    const float* __restrict__ bihb, const float* __restrict__ bhhb) {
    int gt = blockIdx.x * 256 + threadIdx.x;
    int j   = gt & 511;
    int n   = (gt >> 9) & 1023;
    int dir = gt >> 19;
    const float* g   = gates + (size_t)dir * 1024 * 2048 + (size_t)n * 2048;
    const float* bih = dir ? bihb : bihf;
    const float* bhh = dir ? bhhb : bhhf;
    float iv = g[j]        + bih[j]        + bhh[j];
    float fv = g[j + 512]  + bih[j + 512]  + bhh[j + 512];
    float gv = g[j + 1024] + bih[j + 1024] + bhh[j + 1024];
    float ov = g[j + 1536] + bih[j + 1536] + bhh[j + 1536];
    size_t idx = (size_t)dir * 524288 + (size_t)n * 512 + j;
    float cv = sigmoidf_(fv) * c[idx] + sigmoidf_(iv) * tanhf(gv);
    float hv = sigmoidf_(ov) * tanhf(cv);
    c[idx] = cv;
    h[idx] = hv;
    hbf[idx] = f2bf(hv);
}

// feat fp32 + bf16 copy
__global__ __launch_bounds__(256) void k_feat(const float* __restrict__ h,
                                              float* __restrict__ feat,
                                              unsigned short* __restrict__ featbf) {
    int idx = blockIdx.x * 256 + threadIdx.x;
    int n = idx >> 10;
    int d = idx & 1023;
    float v = (d < 512) ? h[(size_t)n * 512 + d]
                        : h[524288 + (size_t)n * 512 + (d - 512)];
    feat[idx] = v;
    featbf[idx] = f2bf(v);
}

// ---------------- generic bf16 GEMM: C[M][N] = A[M][K] @ B[N][K]^T ----------------
__global__ __launch_bounds__(256) void k_gemm_bt(
    const unsigned short* __restrict__ A, int lda,
    const unsigned short* __restrict__ B, int ldb,
    float* __restrict__ C, int ldc, int K) {
    __shared__ unsigned short As[64][72];
    __shared__ unsigned short Bs[64][72];
    const int tid = threadIdx.x;
    const int m0 = blockIdx.x * 64;
    const int n0 = blockIdx.y * 64;
    const int lane = tid & 63;
    const int wvq = tid >> 6;
    const int wm = (wvq >> 1) * 32;
    const int wn = (wvq & 1) * 32;
    const int srow = tid >> 2;
    const int sk0 = (tid & 3) * 16;
    const int arow = lane & 15;
    const int kq = (lane >> 4) * 8;
    f32x4 acc[2][2];
#pragma unroll
    for (int i = 0; i < 2; ++i)
#pragma unroll
        for (int j = 0; j < 2; ++j) acc[i][j] = (f32x4){0.f, 0.f, 0.f, 0.f};
    const unsigned short* ar = A + (size_t)(m0 + srow) * lda;
    const unsigned short* br = B + (size_t)(n0 + srow) * ldb;
    for (int kb = 0; kb < K; kb += 64) {
        int k0 = kb + sk0;
        *(u16x8*)&As[srow][sk0]     = *(const u16x8*)&ar[k0];
        *(u16x8*)&As[srow][sk0 + 8] = *(const u16x8*)&ar[k0 + 8];
        *(u16x8*)&Bs[srow][sk0]     = *(const u16x8*)&br[k0];
        *(u16x8*)&Bs[srow][sk0 + 8] = *(const u16x8*)&br[k0 + 8];
        __syncthreads();
#pragma unroll
        for (int kk = 0; kk < 64; kk += 32) {
            bf16x8 af[2], bfg[2];
#pragma unroll
            for (int i = 0; i < 2; ++i) {
                af[i]  = *(const bf16x8*)&As[wm + i * 16 + arow][kk + kq];
                bfg[i] = *(const bf16x8*)&Bs[wn + i * 16 + arow][kk + kq];
            }
#pragma unroll
            for (int i = 0; i < 2; ++i)
#pragma unroll
                for (int j = 0; j < 2; ++j)
                    acc[i][j] = __builtin_amdgcn_mfma_f32_16x16x32_bf16(
                        af[i], bfg[j], acc[i][j], 0, 0, 0);
        }
        __syncthreads();
    }
    const int rrow = (lane >> 4) * 4;
    const int ccol = lane & 15;
#pragma unroll
    for (int i = 0; i < 2; ++i)
#pragma unroll
        for (int j = 0; j < 2; ++j) {
            int mr = m0 + wm + i * 16 + rrow;
            int nc = n0 + wn + j * 16 + ccol;
#pragma unroll
            for (int r = 0; r < 4; ++r)
                C[(size_t)(mr + r) * ldc + nc] = acc[i][j][r];
        }
}

// ---------------- Phase C: fused GRU (bf16 MFMA GEMM + gate math) ----------------
// out[m][d] for d in [c0, c0+16), m in [0,16). X = [a (+add) | h] (K1 + K2 cols).
// W bf16 [3D][K1+K2] rows: gate r (0..D), z (D..2D), n (2D..3D).
// 4 waves K-split, x-part / h-part kept in separate accumulators (n-gate needs it).
__global__ __launch_bounds__(256) void k_gru_fused(
    const float* __restrict__ aBase, long aStride,
    const float* __restrict__ addBase, long addStride,
    const float* __restrict__ hBase, long hStride,
    const unsigned short* __restrict__ W,
    const float* __restrict__ bih, const float* __restrict__ bhh,
    float* __restrict__ outBase, long outStride,
    int D, int K1, int K2) {
    __shared__ float sA[4][3][16][17];
    __shared__ float sB[4][3][16][17];
    const int tid = threadIdx.x;
    const int lane = tid & 63;
    const int wv = tid >> 6;
    const int c0 = blockIdx.x * 16;
    const int p = lane & 15;
    const int kq = (lane >> 4) * 8;
    const int KW = K1 + K2;
    const int kQ = KW >> 2;        // multiple of 32 for our shapes
    const int kStart = wv * kQ, kEnd = kStart + kQ;
    const bool hasAdd = (addBase != 0);

    f32x4 accA[3], accB[3];
#pragma unroll
    for (int g = 0; g < 3; ++g) {
        accA[g] = (f32x4){0.f, 0.f, 0.f, 0.f};
        accB[g] = (f32x4){0.f, 0.f, 0.f, 0.f};
    }
    const unsigned short* w0 = W + (size_t)(c0 + p) * KW;
    const unsigned short* w1 = W + (size_t)(D + c0 + p) * KW;
    const unsigned short* w2 = W + (size_t)(2 * D + c0 + p) * KW;
    const float* aRow = aBase + (size_t)p * aStride;
    const float* addRow = hasAdd ? addBase + (size_t)p * addStride : (const float*)0;
    const float* hRow = hBase + (size_t)p * hStride;

    for (int k = kStart; k < kEnd; k += 32) {
        int kk = k + kq;
        f32x4 x0, x1;
        bool inA = (k < K1);
        if (inA) {
            x0 = *(const f32x4*)&aRow[kk];
            x1 = *(const f32x4*)&aRow[kk + 4];
            if (hasAdd) {
                f32x4 y0 = *(const f32x4*)&addRow[kk];
                f32x4 y1 = *(const f32x4*)&addRow[kk + 4];
                x0 = x0 + y0; x1 = x1 + y1;
            }
        } else {
            int kh = kk - K1;
            x0 = *(const f32x4*)&hRow[kh];
            x1 = *(const f32x4*)&hRow[kh + 4];
        }
        bf16x8 af = cvt8(x0, x1);
        bf16x8 b0 = *(const bf16x8*)&w0[kk];
        bf16x8 b1 = *(const bf16x8*)&w1[kk];
        bf16x8 b2 = *(const bf16x8*)&w2[kk];
        if (inA) {
            accA[0] = __builtin_amdgcn_mfma_f32_16x16x32_bf16(af, b0, accA[0], 0, 0, 0);
            accA[1] = __builtin_amdgcn_mfma_f32_16x16x32_bf16(af, b1, accA[1], 0, 0, 0);
            accA[2] = __builtin_amdgcn_mfma_f32_16x16x32_bf16(af, b2, accA[2], 0, 0, 0);
        } else {
            accB[0] = __builtin_amdgcn_mfma_f32_16x16x32_bf16(af, b0, accB[0], 0, 0, 0);
            accB[1] = __builtin_amdgcn_mfma_f32_16x16x32_bf16(af, b1, accB[1], 0, 0, 0);
            accB[2] = __builtin_amdgcn_mfma_f32_16x16x32_bf16(af, b2, accB[2], 0, 0, 0);
        }
    }

    const int mB = (lane >> 4) * 4;
#pragma unroll
    for (int g = 0; g < 3; ++g)
#pragma unroll
        for (int r = 0; r < 4; ++r) {
            sA[wv][g][mB + r][p] = accA[g][r];
            sB[wv][g][mB + r][p] = accB[g][r];
        }
    __syncthreads();

    const int m = tid >> 4;
    const int d = tid & 15;
    float ir = 0.f, iz = 0.f, inn = 0.f, hr = 0.f, hz = 0.f, hn = 0.f;
#pragma unroll
    for (int w = 0; w < 4; ++w) {
        ir += sA[w][0][m][d]; iz += sA[w][1][m][d]; inn += sA[w][2][m][d];
        hr += sB[w][0][m][d]; hz += sB[w][1][m][d]; hn += sB[w][2][m][d];
    }
    int gd = c0 + d;
    float rg = sigmoidf_(ir + bih[gd] + hr + bhh[gd]);
    float zg = sigmoidf_(iz + bih[gd + D] + hz + bhh[gd + D]);
    float ng = tanhf(inn + bih[gd + 2 * D] + rg * (hn + bhh[gd + 2 * D]));
    float hp = hBase[(size_t)m * hStride + gd];
    outBase[(size_t)m * outStride + gd] = (1.0f - zg) * ng + zg * hp;
}

// attention: scores over hist[0..i], softmax, ctx. grid = 64: b=blk>>2, part=blk&3.
__global__ __launch_bounds__(256) void k_attn(const float* __restrict__ q,
                                              const float* __restrict__ hist,
                                              float* __restrict__ ctxout, int i) {
    __shared__ float sc[66];
    int b = blockIdx.x >> 2;
    int part = blockIdx.x & 3;
    int tid = threadIdx.x;
    int lane = tid & 63;
    int wv = tid >> 6;
    const float* qb = q + ((size_t)b * 64 + i) * 1024;
    for (int t = wv; t <= i; t += 4) {
        const float* hrow = hist + ((size_t)t * 16 + b) * 1024;
        float s = 0.f;
        for (int d = lane; d < 1024; d += 64) s += qb[d] * hrow[d];
        for (int o = 32; o > 0; o >>= 1) s += __shfl_down(s, o);
        if (lane == 0) sc[t] = s;
    }
    __syncthreads();
    if (tid == 0) {
        float mx = -1e30f;
        for (int t = 0; t <= i; ++t) mx = fmaxf(mx, sc[t]);
        float sum = 0.f;
        for (int t = 0; t <= i; ++t) { float e = __expf(sc[t] - mx); sc[t] = e; sum += e; }
        sc[65] = 1.0f / sum;
    }
    __syncthreads();
    float inv = sc[65];
    int d = part * 256 + tid;
    float s = 0.f;
    for (int t = 0; t <= i; ++t) s += sc[t] * hist[((size_t)t * 16 + b) * 1024 + d];
    ctxout[(size_t)b * 1024 + d] = s * inv;
}

__global__ __launch_bounds__(256) void k_cls(const float* __restrict__ es,
                                             const float* __restrict__ W,
                                             const float* __restrict__ bias,
                                             float* __restrict__ out) {
    int blk = blockIdx.x;
    int b = blk >> 6;
    int u = blk & 63;
    const float* erow = es + ((size_t)u * 16 + b) * 512;
    int tid = threadIdx.x;
    int lane = tid & 63;
    int wv = tid >> 6;
    for (int c = wv; c < 7; c += 4) {
        float s = 0.f;
        for (int k = lane; k < 512; k += 64) s += erow[k] * W[(size_t)c * 512 + k];
        for (int o = 32; o > 0; o >>= 1) s += __shfl_down(s, o);
        if (lane == 0) out[((size_t)b * 64 + u) * 7 + c] = s + bias[c];
    }
}

// ---------------- host ----------------

extern "C" void kernel_launch(void* const* d_in, const int* in_sizes, int n_in,
                              void* d_out, int out_size, void* d_ws, size_t ws_size,
                              hipStream_t stream) {
    (void)in_sizes; (void)n_in; (void)out_size; (void)ws_size;
    const float* x          = (const float*)d_in[0];
    const float* lstm_Wih_f = (const float*)d_in[1];
    const float* lstm_Whh_f = (const float*)d_in[2];
    const float* lstm_bih_f = (const float*)d_in[3];
    const float* lstm_bhh_f = (const float*)d_in[4];
    const float* lstm_Wih_b = (const float*)d_in[5];
    const float* lstm_Whh_b = (const float*)d_in[6];
    const float* lstm_bih_b = (const float*)d_in[7];
    const float* lstm_bhh_b = (const float*)d_in[8];
    const float* gg_Wih = (const float*)d_in[9];
    const float* gg_Whh = (const float*)d_in[10];
    const float* gg_bih = (const float*)d_in[11];
    const float* gg_bhh = (const float*)d_in[12];
    const float* Wg     = (const float*)d_in[13];
    const float* pg_Wih = (const float*)d_in[14];
    const float* pg_Whh = (const float*)d_in[15];
    const float* pg_bih = (const float*)d_in[16];
    const float* pg_bhh = (const float*)d_in[17];
    const float* eg_Wih = (const float*)d_in[18];
    const float* eg_Whh = (const float*)d_in[19];
    const float* eg_bih = (const float*)d_in[20];
    const float* eg_bhh = (const float*)d_in[21];
    const float* cls_W  = (const float*)d_in[22];
    const float* cls_b  = (const float*)d_in[23];

    char* wsp = (char*)d_ws;
    size_t off = 0;
    auto alloc = [&](size_t bytes) -> void* {
        void* p = wsp + off;
        off += (bytes + 255) & ~(size_t)255;
        return p;
    };
    unsigned short* x_bf = (unsigned short*)alloc((size_t)9830400 * 2);
    unsigned short* wcat = (unsigned short*)alloc((size_t)2 * 2048 * 832 * 2);
    unsigned short* hbf  = (unsigned short*)alloc((size_t)2 * 1024 * 512 * 2);
    float* hbuf  = (float*)alloc((size_t)2 * 1024 * 512 * 4);
    float* cbuf  = (float*)alloc((size_t)2 * 1024 * 512 * 4);
    float* gates = (float*)alloc((size_t)2 * 1024 * 2048 * 4);
    float* feat  = (float*)alloc((size_t)1024 * 1024 * 4);
    unsigned short* featbf = (unsigned short*)alloc((size_t)1024 * 1024 * 2);
    float* hist  = (float*)alloc((size_t)65 * 16 * 1024 * 4);
    float* q_all = (float*)alloc((size_t)1024 * 1024 * 4);
    float* ctxb  = (float*)alloc((size_t)16 * 1024 * 4);
    float* pnew  = (float*)alloc((size_t)64 * 16 * 1024 * 4);
    float* esb   = (float*)alloc((size_t)64 * 16 * 512 * 4);
    float* zeroD = (float*)alloc((size_t)16 * 1024 * 4);
    float* zeroH = (float*)alloc((size_t)16 * 512 * 4);
    unsigned short* WgTb = (unsigned short*)alloc((size_t)1024 * 1024 * 2);
    // Aliased decoder weight buffers (gates / x_bf are dead after LSTM phase):
    unsigned short* ggWb = (unsigned short*)gates;                       // 12.58 MB < 16.78 MB
    unsigned short* pgWb = (unsigned short*)x_bf;                        // 12.58 MB
    unsigned short* egWb = (unsigned short*)((char*)x_bf + 12582912);    // +4.72 MB < 19.66 MB

    hipMemsetAsync(hbf, 0, (size_t)2 * 1024 * 512 * 2, stream);
    hipMemsetAsync(cbuf, 0, (size_t)2 * 1024 * 512 * 4, stream);
    hipMemsetAsync(hist, 0, (size_t)65 * 16 * 1024 * 4, stream);
    hipMemsetAsync(zeroD, 0, (size_t)16 * 1024 * 4, stream);
    hipMemsetAsync(zeroH, 0, (size_t)16 * 512 * 4, stream);

    k_f2bf<<<9600, 256, 0, stream>>>(x, x_bf, 9830400);
    k_build_wcat<<<13312, 256, 0, stream>>>(lstm_Wih_f, lstm_Whh_f, lstm_Wih_b, lstm_Whh_b, wcat);

    for (int t = 0; t < 32; ++t) {
        k_lstm_gemm<<<dim3(32, 32), 256, 0, stream>>>(x_bf, hbf, hbf + 524288, wcat, gates, t);
        k_lstm_point<<<4096, 256, 0, stream>>>(gates, cbuf, hbuf, hbf,
                                               lstm_bih_f, lstm_bhh_f, lstm_bih_b, lstm_bhh_b);
    }
    k_feat<<<4096, 256, 0, stream>>>(hbuf, feat, featbf);

    // decoder weight packing (after LSTM: reuses gates / x_bf memory)
    k_cat_w<<<3072, 256, 0, stream>>>(gg_Wih, gg_Whh, ggWb, 1024, 1024);
    k_cat_w<<<3072, 256, 0, stream>>>(pg_Wih, pg_Whh, pgWb, 1024, 1024);
    k_cat_w<<<1536, 256, 0, stream>>>(eg_Wih, eg_Whh, egWb, 1024, 512);
    k_transpose_bf<<<dim3(16, 16), 256, 0, stream>>>(Wg, WgTb);
    // q_all[n][d] = feat[n][:] @ Wg[:,d]  for all steps at once
    k_gemm_bt<<<dim3(16, 16), 256, 0, stream>>>(featbf, 1024, WgTb, 1024, q_all, 1024, 1024);

    float* p0 = zeroD;
    float* p1 = zeroD;
    for (int i = 0; i < 64; ++i) {
        float* psel = (i & 1) ? p1 : p0;
        // gg GRU: x = u + p, h = hist[i] -> hist[i+1]
        k_gru_fused<<<64, 256, 0, stream>>>(feat + (size_t)i * 1024, 65536L, psel, 1024L,
                                            hist + (size_t)i * 16384, 1024L,
                                            ggWb, gg_bih, gg_bhh,
                                            hist + (size_t)(i + 1) * 16384, 1024L,
                                            1024, 1024, 1024);
        k_attn<<<64, 256, 0, stream>>>(q_all, hist, ctxb, i);
        float* pn = pnew + (size_t)i * 16384;
        // pg GRU: x = u + ctx, h = p -> pnew
        k_gru_fused<<<64, 256, 0, stream>>>(feat + (size_t)i * 1024, 65536L, ctxb, 1024L,
                                            psel, 1024L,
                                            pgWb, pg_bih, pg_bhh,
                                            pn, 1024L,
                                            1024, 1024, 1024);
        if (i & 1) p1 = pn; else p0 = pn;
        const float* eprev = (i == 0) ? zeroH : (esb + (size_t)(i - 1) * 8192);
        // eg GRU: x = p_new (K1=1024), h = e (K2=512) -> es[i]
        k_gru_fused<<<32, 256, 0, stream>>>(pn, 1024L, (const float*)0, 0L,
                                            eprev, 512L,
                                            egWb, eg_bih, eg_bhh,
                                            esb + (size_t)i * 8192, 512L,
                                            512, 1024, 512);
    }
    k_cls<<<1024, 256, 0, stream>>>(esb, cls_W, cls_b, (float*)d_out);
}

// Round 4
// 8408.646 us; speedup vs baseline: 4.2606x; 1.4227x over previous
//
#include <hip/hip_runtime.h>
#include <hip/hip_bf16.h>

// Model: BiLSTM (B*U=1024 seqs, W=32 steps, E=300, H=512) -> attention GRU decoder
// (U=64 sequential steps, B=16) -> linear classifier (C=7).
//
// Phase B (LSTM): per-step GEMM M=2048, N=2048, K=832, bf16 MFMA 16x16x32.
// Phase C (decoder): 2 launches/step:
//   A = { gg-GRU (64 blk) || attention (16 blk) || eg-GRU of step i-1 (32 blk) }
//   B = { pg-GRU (64 blk) }
// Each GRU block: 1024 threads / 16 waves, K-split across waves, bf16 MFMA,
// two-phase LDS reduce (52KB), fp32 gate math fused.

#define DEV static __device__ __forceinline__

typedef __attribute__((ext_vector_type(4))) float f32x4;
typedef __attribute__((ext_vector_type(8))) short bf16x8;
typedef __attribute__((ext_vector_type(4))) unsigned short u16x4;
typedef __attribute__((ext_vector_type(8))) unsigned short u16x8;

DEV float sigmoidf_(float x) { return 1.0f / (1.0f + __expf(-x)); }

DEV unsigned short f2bf(float f) {
    union { float f; unsigned u; } v; v.f = f;
    unsigned r = v.u + 0x7FFFu + ((v.u >> 16) & 1u);
    return (unsigned short)(r >> 16);
}

DEV bf16x8 cvt8(f32x4 a, f32x4 b) {
    bf16x8 r;
    r[0] = (short)f2bf(a[0]); r[1] = (short)f2bf(a[1]);
    r[2] = (short)f2bf(a[2]); r[3] = (short)f2bf(a[3]);
    r[4] = (short)f2bf(b[0]); r[5] = (short)f2bf(b[1]);
    r[6] = (short)f2bf(b[2]); r[7] = (short)f2bf(b[3]);
    return r;
}

// ---------------- conversions / packing ----------------

__global__ __launch_bounds__(256) void k_f2bf(const float* __restrict__ in,
                                              unsigned short* __restrict__ out, int n) {
    int idx = (blockIdx.x * 256 + threadIdx.x) * 4;
    if (idx + 3 >= n + 3) return;
    if (idx + 3 < n) {
        f32x4 v = *(const f32x4*)&in[idx];
        u16x4 o;
        o[0] = f2bf(v[0]); o[1] = f2bf(v[1]); o[2] = f2bf(v[2]); o[3] = f2bf(v[3]);
        *(u16x4*)&out[idx] = o;
    } else {
        for (int j = 0; j < 4 && idx + j < n; ++j) out[idx + j] = f2bf(in[idx + j]);
    }
}

__global__ __launch_bounds__(256) void k_build_wcat(
    const float* __restrict__ wihf, const float* __restrict__ whhf,
    const float* __restrict__ wihb, const float* __restrict__ whhb,
    unsigned short* __restrict__ wcat) {
    int gt = blockIdx.x * 256 + threadIdx.x;
    if (gt >= 2 * 2048 * 832) return;
    int k = gt % 832;
    int j = (gt / 832) & 2047;
    int dir = gt / (832 * 2048);
    const float* wih = dir ? wihb : wihf;
    const float* whh = dir ? whhb : whhf;
    float v = 0.0f;
    if (k < 300) v = wih[j * 300 + k];
    else if (k < 812) v = whh[j * 512 + (k - 300)];
    wcat[gt] = f2bf(v);
}

// out[j][k] bf16: k<K1 -> Wih[j][k], else Whh[j][k-K1]. grid = rows.
__global__ __launch_bounds__(256) void k_cat_w(const float* __restrict__ Wih,
                                               const float* __restrict__ Whh,
                                               unsigned short* __restrict__ out,
                                               int K1, int K2) {
    int j = blockIdx.x;
    int KW = K1 + K2;
    const float* a = Wih + (size_t)j * K1;
    const float* b = Whh + (size_t)j * K2;
    unsigned short* o = out + (size_t)j * KW;
    for (int k = threadIdx.x; k < KW; k += 256)
        o[k] = f2bf(k < K1 ? a[k] : b[k - K1]);
}

// WgT[d][k] = bf16(Wg[k][d]), 1024x1024. grid (16,16), 256 threads.
__global__ __launch_bounds__(256) void k_transpose_bf(const float* __restrict__ in,
                                                      unsigned short* __restrict__ out) {
    __shared__ float t[64][65];
    int tid = threadIdx.x;
    int r0 = blockIdx.y * 64, c0 = blockIdx.x * 64;
#pragma unroll
    for (int rep = 0; rep < 16; ++rep) {
        int lin = rep * 256 + tid;
        int r = lin >> 6, c = lin & 63;
        t[r][c] = in[(size_t)(r0 + r) * 1024 + c0 + c];
    }
    __syncthreads();
#pragma unroll
    for (int rep = 0; rep < 16; ++rep) {
        int lin = rep * 256 + tid;
        int d = lin >> 6, k = lin & 63;
        out[(size_t)(c0 + d) * 1024 + r0 + k] = f2bf(t[k][d]);
    }
}

// ---------------- Phase B: LSTM step GEMM (bf16 MFMA) ----------------

__global__ __launch_bounds__(256) void k_lstm_gemm(
    const unsigned short* __restrict__ xbf,   // (1024,32,300)
    const unsigned short* __restrict__ hbff,  // (1024,512)
    const unsigned short* __restrict__ hbfb,  // (1024,512)
    const unsigned short* __restrict__ wcat,  // (2,2048,832)
    float* __restrict__ gates,                // (2,1024,2048)
    int t) {
    __shared__ unsigned short As[64][72];
    __shared__ unsigned short Ws[64][72];

    const int tid  = threadIdx.x;
    const int br   = blockIdx.x;
    const int bc   = blockIdx.y;
    const int row0 = br * 64;
    const int dir  = row0 >> 10;
    const int n0   = row0 & 1023;
    const int col0 = bc * 64;
    const int teff = dir ? (31 - t) : t;
    const unsigned short* hbf = dir ? hbfb : hbff;
    const unsigned short* wb  = wcat + (size_t)dir * 2048 * 832;

    const int lane = tid & 63;
    const int wv   = tid >> 6;
    const int wm   = (wv >> 1) * 32;
    const int wn   = (wv & 1) * 32;
    const int srow = tid >> 2;
    const int sk0  = (tid & 3) * 16;
    const int arow = lane & 15;
    const int kq   = (lane >> 4) * 8;

    f32x4 acc[2][2];
#pragma unroll
    for (int i = 0; i < 2; ++i)
#pragma unroll
        for (int j = 0; j < 2; ++j) acc[i][j] = (f32x4){0.f, 0.f, 0.f, 0.f};

    const int nrow = n0 + srow;
    const int wrow = col0 + srow;
    const unsigned short* xrow = xbf + ((size_t)nrow * 32 + teff) * 300;
    const unsigned short* hrow = hbf + (size_t)nrow * 512;
    const unsigned short* wrp  = wb + (size_t)wrow * 832;

    for (int kt = 0; kt < 13; ++kt) {
        const int kb = kt * 64 + sk0;
#pragma unroll
        for (int e = 0; e < 16; ++e) {
            int k = kb + e;
            unsigned short v;
            if (k < 300) v = xrow[k];
            else if (k < 812) v = hrow[k - 300];
            else v = 0;
            As[srow][sk0 + e] = v;
            Ws[srow][sk0 + e] = wrp[k];
        }
        __syncthreads();
#pragma unroll
        for (int kk = 0; kk < 64; kk += 32) {
            bf16x8 af[2], bfg[2];
#pragma unroll
            for (int i = 0; i < 2; ++i) {
                af[i]  = *(const bf16x8*)&As[wm + i * 16 + arow][kk + kq];
                bfg[i] = *(const bf16x8*)&Ws[wn + i * 16 + arow][kk + kq];
            }
#pragma unroll
            for (int i = 0; i < 2; ++i)
#pragma unroll
                for (int j = 0; j < 2; ++j)
                    acc[i][j] = __builtin_amdgcn_mfma_f32_16x16x32_bf16(
                        af[i], bfg[j], acc[i][j], 0, 0, 0);
        }
        __syncthreads();
    }

    const int rrow = (lane >> 4) * 4;
    const int ccol = lane & 15;
    float* gout = gates + (size_t)dir * 1024 * 2048;
#pragma unroll
    for (int i = 0; i < 2; ++i)
#pragma unroll
        for (int j = 0; j < 2; ++j) {
            int nrw = n0 + wm + i * 16 + rrow;
            int cl  = col0 + wn + j * 16 + ccol;
#pragma unroll
            for (int r = 0; r < 4; ++r)
                gout[(size_t)(nrw + r) * 2048 + cl] = acc[i][j][r];
        }
}

__global__ __launch_bounds__(256) void k_lstm_point(
    const float* __restrict__ gates, float* __restrict__ c, float* __restrict__ h,
    unsigned short* __restrict__ hbf,
    const float* __restrict__ bihf, const float* __restrict__ bhhf,
    const float* __restrict__ bihb, const float* __restrict__ bhhb) {
    int gt = blockIdx.x * 256 + threadIdx.x;
    int j   = gt & 511;
    int n   = (gt >> 9) & 1023;
    int dir = gt >> 19;
    const float* g   = gates + (size_t)dir * 1024 * 2048 + (size_t)n * 2048;
    const float* bih = dir ? bihb : bihf;
    const float* bhh = dir ? bhhb : bhhf;
    float iv = g[j]        + bih[j]        + bhh[j];
    float fv = g[j + 512]  + bih[j + 512]  + bhh[j + 512];
    float gv = g[j + 1024] + bih[j + 1024] + bhh[j + 1024];
    float ov = g[j + 1536] + bih[j + 1536] + bhh[j + 1536];
    size_t idx = (size_t)dir * 524288 + (size_t)n * 512 + j;
    float cv = sigmoidf_(fv) * c[idx] + sigmoidf_(iv) * tanhf(gv);
    float hv = sigmoidf_(ov) * tanhf(cv);
    c[idx] = cv;
    h[idx] = hv;
    hbf[idx] = f2bf(hv);
}

__global__ __launch_bounds__(256) void k_feat(const float* __restrict__ h,
                                              float* __restrict__ feat,
                                              unsigned short* __restrict__ featbf) {
    int idx = blockIdx.x * 256 + threadIdx.x;
    int n = idx >> 10;
    int d = idx & 1023;
    float v = (d < 512) ? h[(size_t)n * 512 + d]
                        : h[524288 + (size_t)n * 512 + (d - 512)];
    feat[idx] = v;
    featbf[idx] = f2bf(v);
}

// ---------------- generic bf16 GEMM: C[M][N] = A[M][K] @ B[N][K]^T ----------------
__global__ __launch_bounds__(256) void k_gemm_bt(
    const unsigned short* __restrict__ A, int lda,
    const unsigned short* __restrict__ B, int ldb,
    float* __restrict__ C, int ldc, int K) {
    __shared__ unsigned short As[64][72];
    __shared__ unsigned short Bs[64][72];
    const int tid = threadIdx.x;
    const int m0 = blockIdx.x * 64;
    const int n0 = blockIdx.y * 64;
    const int lane = tid & 63;
    const int wvq = tid >> 6;
    const int wm = (wvq >> 1) * 32;
    const int wn = (wvq & 1) * 32;
    const int srow = tid >> 2;
    const int sk0 = (tid & 3) * 16;
    const int arow = lane & 15;
    const int kq = (lane >> 4) * 8;
    f32x4 acc[2][2];
#pragma unroll
    for (int i = 0; i < 2; ++i)
#pragma unroll
        for (int j = 0; j < 2; ++j) acc[i][j] = (f32x4){0.f, 0.f, 0.f, 0.f};
    const unsigned short* ar = A + (size_t)(m0 + srow) * lda;
    const unsigned short* br = B + (size_t)(n0 + srow) * ldb;
    for (int kb = 0; kb < K; kb += 64) {
        int k0 = kb + sk0;
        *(u16x8*)&As[srow][sk0]     = *(const u16x8*)&ar[k0];
        *(u16x8*)&As[srow][sk0 + 8] = *(const u16x8*)&ar[k0 + 8];
        *(u16x8*)&Bs[srow][sk0]     = *(const u16x8*)&br[k0];
        *(u16x8*)&Bs[srow][sk0 + 8] = *(const u16x8*)&br[k0 + 8];
        __syncthreads();
#pragma unroll
        for (int kk = 0; kk < 64; kk += 32) {
            bf16x8 af[2], bfg[2];
#pragma unroll
            for (int i = 0; i < 2; ++i) {
                af[i]  = *(const bf16x8*)&As[wm + i * 16 + arow][kk + kq];
                bfg[i] = *(const bf16x8*)&Bs[wn + i * 16 + arow][kk + kq];
            }
#pragma unroll
            for (int i = 0; i < 2; ++i)
#pragma unroll
                for (int j = 0; j < 2; ++j)
                    acc[i][j] = __builtin_amdgcn_mfma_f32_16x16x32_bf16(
                        af[i], bfg[j], acc[i][j], 0, 0, 0);
        }
        __syncthreads();
    }
    const int rrow = (lane >> 4) * 4;
    const int ccol = lane & 15;
#pragma unroll
    for (int i = 0; i < 2; ++i)
#pragma unroll
        for (int j = 0; j < 2; ++j) {
            int mr = m0 + wm + i * 16 + rrow;
            int nc = n0 + wn + j * 16 + ccol;
#pragma unroll
            for (int r = 0; r < 4; ++r)
                C[(size_t)(mr + r) * ldc + nc] = acc[i][j][r];
        }
}

// ---------------- Phase C: decoder building blocks ----------------

// 16-wave GRU block: out[m][c0+d] for d in [0,16), m in [0,16).
// X = [a (+add) | h] (K1 + K2). W bf16 [3D][K1+K2] rows (r, z, n gates).
// Waves K-split (KW/16 each); x-part and h-part accumulated separately
// (n-gate needs them split). Two-phase LDS reduce in sred[16][3][16][17].
DEV void gru_block16(
    int c0,
    const float* __restrict__ aBase, long aStride,
    const float* __restrict__ addBase, long addStride,
    const float* __restrict__ hBase, long hStride,
    const unsigned short* __restrict__ W,
    const float* __restrict__ bih, const float* __restrict__ bhh,
    float* __restrict__ outBase, long outStride,
    int D, int K1, int K2,
    float (*sred)[3][16][17]) {
    const int tid = threadIdx.x;
    const int lane = tid & 63;
    const int wv = tid >> 6;          // 0..15
    const int p = lane & 15;
    const int kq = (lane >> 4) * 8;
    const int KW = K1 + K2;
    const int Kc = KW >> 4;           // per-wave K span (multiple of 32 for our shapes)
    const int kStart = wv * Kc;
    const bool hasAdd = (addBase != nullptr);

    f32x4 accA[3], accB[3];
#pragma unroll
    for (int g = 0; g < 3; ++g) {
        accA[g] = (f32x4){0.f, 0.f, 0.f, 0.f};
        accB[g] = (f32x4){0.f, 0.f, 0.f, 0.f};
    }
    const unsigned short* w0 = W + (size_t)(c0 + p) * KW;
    const unsigned short* w1 = w0 + (size_t)D * KW;
    const unsigned short* w2 = w1 + (size_t)D * KW;
    const float* aRow = aBase + (size_t)p * aStride;
    const float* addRow = hasAdd ? addBase + (size_t)p * addStride : (const float*)0;
    const float* hRow = hBase + (size_t)p * hStride;

    for (int k = kStart; k < kStart + Kc; k += 32) {
        const int kk = k + kq;
        f32x4 x0, x1;
        const bool inA = (k < K1);
        if (inA) {
            x0 = *(const f32x4*)&aRow[kk];
            x1 = *(const f32x4*)&aRow[kk + 4];
            if (hasAdd) {
                f32x4 y0 = *(const f32x4*)&addRow[kk];
                f32x4 y1 = *(const f32x4*)&addRow[kk + 4];
                x0 = x0 + y0; x1 = x1 + y1;
            }
        } else {
            x0 = *(const f32x4*)&hRow[kk - K1];
            x1 = *(const f32x4*)&hRow[kk - K1 + 4];
        }
        bf16x8 af = cvt8(x0, x1);
        bf16x8 b0 = *(const bf16x8*)&w0[kk];
        bf16x8 b1 = *(const bf16x8*)&w1[kk];
        bf16x8 b2 = *(const bf16x8*)&w2[kk];
        if (inA) {
            accA[0] = __builtin_amdgcn_mfma_f32_16x16x32_bf16(af, b0, accA[0], 0, 0, 0);
            accA[1] = __builtin_amdgcn_mfma_f32_16x16x32_bf16(af, b1, accA[1], 0, 0, 0);
            accA[2] = __builtin_amdgcn_mfma_f32_16x16x32_bf16(af, b2, accA[2], 0, 0, 0);
        } else {
            accB[0] = __builtin_amdgcn_mfma_f32_16x16x32_bf16(af, b0, accB[0], 0, 0, 0);
            accB[1] = __builtin_amdgcn_mfma_f32_16x16x32_bf16(af, b1, accB[1], 0, 0, 0);
            accB[2] = __builtin_amdgcn_mfma_f32_16x16x32_bf16(af, b2, accB[2], 0, 0, 0);
        }
    }

    const int mB = (lane >> 4) * 4;
    const int m = tid >> 4;   // finish mapping (tid < 256)
    const int d = tid & 15;

    // phase 1: reduce x-part
#pragma unroll
    for (int g = 0; g < 3; ++g)
#pragma unroll
        for (int r = 0; r < 4; ++r)
            sred[wv][g][mB + r][p] = accA[g][r];
    __syncthreads();
    float ir = 0.f, iz = 0.f, inn = 0.f;
    if (tid < 256) {
#pragma unroll
        for (int w = 0; w < 16; ++w) {
            ir += sred[w][0][m][d]; iz += sred[w][1][m][d]; inn += sred[w][2][m][d];
        }
    }
    __syncthreads();
    // phase 2: reduce h-part
#pragma unroll
    for (int g = 0; g < 3; ++g)
#pragma unroll
        for (int r = 0; r < 4; ++r)
            sred[wv][g][mB + r][p] = accB[g][r];
    __syncthreads();
    if (tid < 256) {
        float hr = 0.f, hz = 0.f, hn = 0.f;
#pragma unroll
        for (int w = 0; w < 16; ++w) {
            hr += sred[w][0][m][d]; hz += sred[w][1][m][d]; hn += sred[w][2][m][d];
        }
        int gd = c0 + d;
        float rg = sigmoidf_(ir + bih[gd] + hr + bhh[gd]);
        float zg = sigmoidf_(iz + bih[gd + D] + hz + bhh[gd + D]);
        float ng = tanhf(inn + bih[gd + 2 * D] + rg * (hn + bhh[gd + 2 * D]));
        float hp = hBase[(size_t)m * hStride + gd];
        outBase[(size_t)m * outStride + gd] = (1.0f - zg) * ng + zg * hp;
    }
}

// attention block (1024 thr): scores over hist[0..i] for batch b, softmax, ctx.
DEV void attn_block(int b, int i, const float* __restrict__ q_all,
                    const float* __restrict__ hist, float* __restrict__ ctxout,
                    float* __restrict__ satt) {
    const int tid = threadIdx.x;
    const int lane = tid & 63;
    const int wv = tid >> 6;
    const float* qb = q_all + ((size_t)b * 64 + i) * 1024;
    for (int t = wv; t <= i; t += 16) {
        const float* hrow = hist + ((size_t)t * 16 + b) * 1024;
        float s = 0.f;
        for (int dd = lane; dd < 1024; dd += 64) s += qb[dd] * hrow[dd];
        for (int o = 32; o > 0; o >>= 1) s += __shfl_down(s, o);
        if (lane == 0) satt[t] = s;
    }
    __syncthreads();
    if (wv == 0) {
        float v = (lane <= i) ? satt[lane] : -3.0e38f;
        float mx = v;
        for (int o = 32; o > 0; o >>= 1) mx = fmaxf(mx, __shfl_xor(mx, o));
        float e = (lane <= i) ? __expf(v - mx) : 0.f;
        float sum = e;
        for (int o = 32; o > 0; o >>= 1) sum += __shfl_xor(sum, o);
        if (lane <= i) satt[lane] = e / sum;
    }
    __syncthreads();
    const int dd = tid;
    float s = 0.f;
    for (int t = 0; t <= i; ++t)
        s += satt[t] * hist[((size_t)t * 16 + b) * 1024 + dd];
    ctxout[(size_t)b * 1024 + dd] = s;
}

// Launch A: blocks [0,64) gg-GRU, [64,80) attention, [80,112) eg-GRU of step i-1.
__global__ __launch_bounds__(1024) void k_dec_A(
    const float* __restrict__ feat, const float* __restrict__ q_all,
    float* __restrict__ hist, const float* __restrict__ psel,
    const unsigned short* __restrict__ ggW,
    const float* __restrict__ gg_bih, const float* __restrict__ gg_bhh,
    float* __restrict__ ctxb,
    const float* __restrict__ pn_prev, const float* __restrict__ e_prev,
    float* __restrict__ es_prev_out,
    const unsigned short* __restrict__ egW,
    const float* __restrict__ eg_bih, const float* __restrict__ eg_bhh,
    int i) {
    __shared__ float sred[16][3][16][17];
    __shared__ float satt[80];
    const int blk = blockIdx.x;
    if (blk < 64) {
        if (i >= 64) return;
        gru_block16(blk * 16, feat + (size_t)i * 1024, 65536L, psel, 1024L,
                    hist + (size_t)i * 16384, 1024L, ggW, gg_bih, gg_bhh,
                    hist + (size_t)(i + 1) * 16384, 1024L, 1024, 1024, 1024, sred);
    } else if (blk < 80) {
        if (i >= 64) return;
        attn_block(blk - 64, i, q_all, hist, ctxb, satt);
    } else {
        if (i < 1) return;
        gru_block16((blk - 80) * 16, pn_prev, 1024L, (const float*)0, 0L,
                    e_prev, 512L, egW, eg_bih, eg_bhh,
                    es_prev_out, 512L, 512, 1024, 512, sred);
    }
}

// Launch B: pg-GRU (64 blocks).
__global__ __launch_bounds__(1024) void k_dec_B(
    const float* __restrict__ feat, const float* __restrict__ ctxb,
    const float* __restrict__ psel,
    const unsigned short* __restrict__ pgW,
    const float* __restrict__ pg_bih, const float* __restrict__ pg_bhh,
    float* __restrict__ pn, int i) {
    __shared__ float sred[16][3][16][17];
    gru_block16(blockIdx.x * 16, feat + (size_t)i * 1024, 65536L, ctxb, 1024L,
                psel, 1024L, pgW, pg_bih, pg_bhh, pn, 1024L, 1024, 1024, 1024, sred);
}

__global__ __launch_bounds__(256) void k_cls(const float* __restrict__ es,
                                             const float* __restrict__ W,
                                             const float* __restrict__ bias,
                                             float* __restrict__ out) {
    int blk = blockIdx.x;
    int b = blk >> 6;
    int u = blk & 63;
    const float* erow = es + ((size_t)u * 16 + b) * 512;
    int tid = threadIdx.x;
    int lane = tid & 63;
    int wv = tid >> 6;
    for (int c = wv; c < 7; c += 4) {
        float s = 0.f;
        for (int k = lane; k < 512; k += 64) s += erow[k] * W[(size_t)c * 512 + k];
        for (int o = 32; o > 0; o >>= 1) s += __shfl_down(s, o);
        if (lane == 0) out[((size_t)b * 64 + u) * 7 + c] = s + bias[c];
    }
}

// ---------------- host ----------------

extern "C" void kernel_launch(void* const* d_in, const int* in_sizes, int n_in,
                              void* d_out, int out_size, void* d_ws, size_t ws_size,
                              hipStream_t stream) {
    (void)in_sizes; (void)n_in; (void)out_size; (void)ws_size;
    const float* x          = (const float*)d_in[0];
    const float* lstm_Wih_f = (const float*)d_in[1];
    const float* lstm_Whh_f = (const float*)d_in[2];
    const float* lstm_bih_f = (const float*)d_in[3];
    const float* lstm_bhh_f = (const float*)d_in[4];
    const float* lstm_Wih_b = (const float*)d_in[5];
    const float* lstm_Whh_b = (const float*)d_in[6];
    const float* lstm_bih_b = (const float*)d_in[7];
    const float* lstm_bhh_b = (const float*)d_in[8];
    const float* gg_Wih = (const float*)d_in[9];
    const float* gg_Whh = (const float*)d_in[10];
    const float* gg_bih = (const float*)d_in[11];
    const float* gg_bhh = (const float*)d_in[12];
    const float* Wg     = (const float*)d_in[13];
    const float* pg_Wih = (const float*)d_in[14];
    const float* pg_Whh = (const float*)d_in[15];
    const float* pg_bih = (const float*)d_in[16];
    const float* pg_bhh = (const float*)d_in[17];
    const float* eg_Wih = (const float*)d_in[18];
    const float* eg_Whh = (const float*)d_in[19];
    const float* eg_bih = (const float*)d_in[20];
    const float* eg_bhh = (const float*)d_in[21];
    const float* cls_W  = (const float*)d_in[22];
    const float* cls_b  = (const float*)d_in[23];

    char* wsp = (char*)d_ws;
    size_t off = 0;
    auto alloc = [&](size_t bytes) -> void* {
        void* p = wsp + off;
        off += (bytes + 255) & ~(size_t)255;
        return p;
    };
    unsigned short* x_bf = (unsigned short*)alloc((size_t)9830400 * 2);
    unsigned short* wcat = (unsigned short*)alloc((size_t)2 * 2048 * 832 * 2);
    unsigned short* hbf  = (unsigned short*)alloc((size_t)2 * 1024 * 512 * 2);
    float* hbuf  = (float*)alloc((size_t)2 * 1024 * 512 * 4);
    float* cbuf  = (float*)alloc((size_t)2 * 1024 * 512 * 4);
    float* gates = (float*)alloc((size_t)2 * 1024 * 2048 * 4);
    float* feat  = (float*)alloc((size_t)1024 * 1024 * 4);
    unsigned short* featbf = (unsigned short*)alloc((size_t)1024 * 1024 * 2);
    float* hist  = (float*)alloc((size_t)65 * 16 * 1024 * 4);
    float* q_all = (float*)alloc((size_t)1024 * 1024 * 4);
    float* ctxb  = (float*)alloc((size_t)16 * 1024 * 4);
    float* pnew  = (float*)alloc((size_t)64 * 16 * 1024 * 4);
    float* esb   = (float*)alloc((size_t)64 * 16 * 512 * 4);
    float* zeroD = (float*)alloc((size_t)16 * 1024 * 4);
    float* zeroH = (float*)alloc((size_t)16 * 512 * 4);
    unsigned short* WgTb = (unsigned short*)alloc((size_t)1024 * 1024 * 2);
    // Aliased decoder weight buffers (gates / x_bf are dead after LSTM phase):
    unsigned short* ggWb = (unsigned short*)gates;                       // 12.58 MB < 16.78 MB
    unsigned short* pgWb = (unsigned short*)x_bf;                        // 12.58 MB
    unsigned short* egWb = (unsigned short*)((char*)x_bf + 12582912);    // +4.72 MB < 19.66 MB

    hipMemsetAsync(hbf, 0, (size_t)2 * 1024 * 512 * 2, stream);
    hipMemsetAsync(cbuf, 0, (size_t)2 * 1024 * 512 * 4, stream);
    hipMemsetAsync(hist, 0, (size_t)65 * 16 * 1024 * 4, stream);
    hipMemsetAsync(zeroD, 0, (size_t)16 * 1024 * 4, stream);
    hipMemsetAsync(zeroH, 0, (size_t)16 * 512 * 4, stream);

    k_f2bf<<<9600, 256, 0, stream>>>(x, x_bf, 9830400);
    k_build_wcat<<<13312, 256, 0, stream>>>(lstm_Wih_f, lstm_Whh_f, lstm_Wih_b, lstm_Whh_b, wcat);

    for (int t = 0; t < 32; ++t) {
        k_lstm_gemm<<<dim3(32, 32), 256, 0, stream>>>(x_bf, hbf, hbf + 524288, wcat, gates, t);
        k_lstm_point<<<4096, 256, 0, stream>>>(gates, cbuf, hbuf, hbf,
                                               lstm_bih_f, lstm_bhh_f, lstm_bih_b, lstm_bhh_b);
    }
    k_feat<<<4096, 256, 0, stream>>>(hbuf, feat, featbf);

    // decoder weight packing (after LSTM: reuses gates / x_bf memory)
    k_cat_w<<<3072, 256, 0, stream>>>(gg_Wih, gg_Whh, ggWb, 1024, 1024);
    k_cat_w<<<3072, 256, 0, stream>>>(pg_Wih, pg_Whh, pgWb, 1024, 1024);
    k_cat_w<<<1536, 256, 0, stream>>>(eg_Wih, eg_Whh, egWb, 1024, 512);
    k_transpose_bf<<<dim3(16, 16), 256, 0, stream>>>(Wg, WgTb);
    k_gemm_bt<<<dim3(16, 16), 256, 0, stream>>>(featbf, 1024, WgTb, 1024, q_all, 1024, 1024);

    float* p0 = zeroD;
    float* p1 = zeroD;
    for (int i = 0; i <= 64; ++i) {
        float* psel = (i & 1) ? p1 : p0;
        const float* pn_prev = (i >= 1) ? pnew + (size_t)(i - 1) * 16384 : (const float*)0;
        const float* e_prev  = (i >= 2) ? esb + (size_t)(i - 2) * 8192 : zeroH;
        float* es_prev_out   = (i >= 1) ? esb + (size_t)(i - 1) * 8192 : (float*)0;
        // A: gg_i || attn_i || eg_{i-1}
        k_dec_A<<<112, 1024, 0, stream>>>(feat, q_all, hist, psel,
                                          ggWb, gg_bih, gg_bhh, ctxb,
                                          pn_prev, e_prev, es_prev_out,
                                          egWb, eg_bih, eg_bhh, i);
        if (i < 64) {
            float* pn = pnew + (size_t)i * 16384;
            // B: pg_i
            k_dec_B<<<64, 1024, 0, stream>>>(feat, ctxb, psel, pgWb, pg_bih, pg_bhh, pn, i);
            if (i & 1) p1 = pn; else p0 = pn;
        }
    }
    k_cls<<<1024, 256, 0, stream>>>(esb, cls_W, cls_b, (float*)d_out);
}

// Round 5
// 3119.690 us; speedup vs baseline: 11.4839x; 2.6953x over previous
//
#include <hip/hip_runtime.h>
#include <hip/hip_bf16.h>

// Model: BiLSTM (B*U=1024 seqs, W=32 steps, E=300, H=512) -> attention GRU decoder
// (U=64 sequential steps, B=16) -> linear classifier (C=7).
//
// Phase B (LSTM): per-step GEMM M=2048, N=2048, K=832 (=320 x-part + 512 h-part),
//   bf16 MFMA 16x16x32, 64x64 tiles, fully vectorized u16x8/b128 staging.
//   x pre-padded+reversed into xpad[2][32][1024][320] so staging has no branches.
// Phase C (decoder): 2 launches/step:
//   A = { gg-GRU (64 blk) || attention (16 blk) || eg-GRU of step i-1 (32 blk) }
//   B = { pg-GRU (64 blk) }, 16-wave GRU blocks, bf16 MFMA, LDS tree reduce.

#define DEV static __device__ __forceinline__

typedef __attribute__((ext_vector_type(4))) float f32x4;
typedef __attribute__((ext_vector_type(8))) short bf16x8;
typedef __attribute__((ext_vector_type(8))) unsigned short u16x8;

DEV float sigmoidf_(float x) { return 1.0f / (1.0f + __expf(-x)); }

DEV unsigned short f2bf(float f) {
    union { float f; unsigned u; } v; v.f = f;
    unsigned r = v.u + 0x7FFFu + ((v.u >> 16) & 1u);
    return (unsigned short)(r >> 16);
}

DEV bf16x8 cvt8(f32x4 a, f32x4 b) {
    bf16x8 r;
    r[0] = (short)f2bf(a[0]); r[1] = (short)f2bf(a[1]);
    r[2] = (short)f2bf(a[2]); r[3] = (short)f2bf(a[3]);
    r[4] = (short)f2bf(b[0]); r[5] = (short)f2bf(b[1]);
    r[6] = (short)f2bf(b[2]); r[7] = (short)f2bf(b[3]);
    return r;
}

// ---------------- packing ----------------

// xpad[dir][t][n][kp] bf16: kp<300 -> x[n][teff][kp] (teff reversed for dir=1), else 0.
__global__ __launch_bounds__(256) void k_build_xpad(const float* __restrict__ x,
                                                    unsigned short* __restrict__ xpad) {
    size_t gt = (size_t)blockIdx.x * 256 + threadIdx.x;  // 2*32*1024*320 = 20971520
    if (gt >= (size_t)20971520) return;
    int kp = (int)(gt % 320);
    int n = (int)((gt / 320) & 1023);
    int t = (int)((gt / (320 * 1024)) & 31);
    int dir = (int)(gt / ((size_t)320 * 1024 * 32));
    int teff = dir ? (31 - t) : t;
    float v = (kp < 300) ? x[((size_t)n * 32 + teff) * 300 + kp] : 0.0f;
    xpad[gt] = f2bf(v);
}

// Wcat[dir][j][k]: k<300 -> Wih[j][k]; 320<=k<832 -> Whh[j][k-320]; else 0.  (2,2048,832) bf16
__global__ __launch_bounds__(256) void k_build_wcat(
    const float* __restrict__ wihf, const float* __restrict__ whhf,
    const float* __restrict__ wihb, const float* __restrict__ whhb,
    unsigned short* __restrict__ wcat) {
    int gt = blockIdx.x * 256 + threadIdx.x;
    if (gt >= 2 * 2048 * 832) return;
    int k = gt % 832;
    int j = (gt / 832) & 2047;
    int dir = gt / (832 * 2048);
    const float* wih = dir ? wihb : wihf;
    const float* whh = dir ? whhb : whhf;
    float v = 0.0f;
    if (k < 300) v = wih[j * 300 + k];
    else if (k >= 320) v = whh[j * 512 + (k - 320)];
    wcat[gt] = f2bf(v);
}

// out[j][k] bf16: k<K1 -> Wih[j][k], else Whh[j][k-K1]. grid = rows.
__global__ __launch_bounds__(256) void k_cat_w(const float* __restrict__ Wih,
                                               const float* __restrict__ Whh,
                                               unsigned short* __restrict__ out,
                                               int K1, int K2) {
    int j = blockIdx.x;
    int KW = K1 + K2;
    const float* a = Wih + (size_t)j * K1;
    const float* b = Whh + (size_t)j * K2;
    unsigned short* o = out + (size_t)j * KW;
    for (int k = threadIdx.x; k < KW; k += 256)
        o[k] = f2bf(k < K1 ? a[k] : b[k - K1]);
}

// WgT[d][k] = bf16(Wg[k][d]), 1024x1024. grid (16,16), 256 threads.
__global__ __launch_bounds__(256) void k_transpose_bf(const float* __restrict__ in,
                                                      unsigned short* __restrict__ out) {
    __shared__ float t[64][65];
    int tid = threadIdx.x;
    int r0 = blockIdx.y * 64, c0 = blockIdx.x * 64;
#pragma unroll
    for (int rep = 0; rep < 16; ++rep) {
        int lin = rep * 256 + tid;
        int r = lin >> 6, c = lin & 63;
        t[r][c] = in[(size_t)(r0 + r) * 1024 + c0 + c];
    }
    __syncthreads();
#pragma unroll
    for (int rep = 0; rep < 16; ++rep) {
        int lin = rep * 256 + tid;
        int d = lin >> 6, k = lin & 63;
        out[(size_t)(c0 + d) * 1024 + r0 + k] = f2bf(t[k][d]);
    }
}

// ---------------- Phase B: LSTM step GEMM (bf16 MFMA, vectorized staging) ----------------
// gates[dir][n][j] = sum_k A[n][k] * Wcat[dir][j][k]
// A[n][k] = k<320 ? xpad[dir][t][n][k] : hbf[dir][n][k-320]

__global__ __launch_bounds__(256) void k_lstm_gemm(
    const unsigned short* __restrict__ xpad,  // (2,32,1024,320)
    const unsigned short* __restrict__ hbf,   // (2,1024,512)
    const unsigned short* __restrict__ wcat,  // (2,2048,832)
    float* __restrict__ gates,                // (2,1024,2048)
    int t) {
    __shared__ unsigned short As[64][72];
    __shared__ unsigned short Ws[64][72];

    const int tid  = threadIdx.x;
    const int br   = blockIdx.x;       // 0..31 M-tiles
    const int bc   = blockIdx.y;       // 0..31 N-tiles
    const int row0 = br * 64;
    const int dir  = row0 >> 10;
    const int n0   = row0 & 1023;
    const int col0 = bc * 64;

    const int lane = tid & 63;
    const int wv   = tid >> 6;
    const int wm   = (wv >> 1) * 32;
    const int wn   = (wv & 1) * 32;
    const int srow = tid >> 2;            // 0..63 staging row
    const int sk0  = (tid & 3) * 16;      // 16 k per thread
    const int arow = lane & 15;
    const int kq   = (lane >> 4) * 8;

    f32x4 acc[2][2];
#pragma unroll
    for (int i = 0; i < 2; ++i)
#pragma unroll
        for (int j = 0; j < 2; ++j) acc[i][j] = (f32x4){0.f, 0.f, 0.f, 0.f};

    const unsigned short* xrow = xpad + (((size_t)dir * 32 + t) * 1024 + n0 + srow) * 320;
    const unsigned short* hrow = hbf + ((size_t)dir * 1024 + n0 + srow) * 512;
    const unsigned short* wrp  = wcat + ((size_t)dir * 2048 + col0 + srow) * 832;

    for (int kt = 0; kt < 13; ++kt) {
        const unsigned short* asrc = (kt < 5) ? (xrow + kt * 64) : (hrow + (kt * 64 - 320));
        const unsigned short* wsrc = wrp + kt * 64;
        *(u16x8*)&As[srow][sk0]     = *(const u16x8*)&asrc[sk0];
        *(u16x8*)&As[srow][sk0 + 8] = *(const u16x8*)&asrc[sk0 + 8];
        *(u16x8*)&Ws[srow][sk0]     = *(const u16x8*)&wsrc[sk0];
        *(u16x8*)&Ws[srow][sk0 + 8] = *(const u16x8*)&wsrc[sk0 + 8];
        __syncthreads();
#pragma unroll
        for (int kk = 0; kk < 64; kk += 32) {
            bf16x8 af[2], bfg[2];
#pragma unroll
            for (int i = 0; i < 2; ++i) {
                af[i]  = *(const bf16x8*)&As[wm + i * 16 + arow][kk + kq];
                bfg[i] = *(const bf16x8*)&Ws[wn + i * 16 + arow][kk + kq];
            }
#pragma unroll
            for (int i = 0; i < 2; ++i)
#pragma unroll
                for (int j = 0; j < 2; ++j)
                    acc[i][j] = __builtin_amdgcn_mfma_f32_16x16x32_bf16(
                        af[i], bfg[j], acc[i][j], 0, 0, 0);
        }
        __syncthreads();
    }

    const int rrow = (lane >> 4) * 4;
    const int ccol = lane & 15;
    float* gout = gates + (size_t)dir * 1024 * 2048;
#pragma unroll
    for (int i = 0; i < 2; ++i)
#pragma unroll
        for (int j = 0; j < 2; ++j) {
            int nrw = n0 + wm + i * 16 + rrow;
            int cl  = col0 + wn + j * 16 + ccol;
#pragma unroll
            for (int r = 0; r < 4; ++r)
                gout[(size_t)(nrw + r) * 2048 + cl] = acc[i][j][r];
        }
}

__global__ __launch_bounds__(256) void k_lstm_point(
    const float* __restrict__ gates, float* __restrict__ c, float* __restrict__ h,
    unsigned short* __restrict__ hbf,
    const float* __restrict__ bihf, const float* __restrict__ bhhf,
    const float* __restrict__ bihb, const float* __restrict__ bhhb) {
    int gt = blockIdx.x * 256 + threadIdx.x;
    int j   = gt & 511;
    int n   = (gt >> 9) & 1023;
    int dir = gt >> 19;
    const float* g   = gates + (size_t)dir * 1024 * 2048 + (size_t)n * 2048;
    const float* bih = dir ? bihb : bihf;
    const float* bhh = dir ? bhhb : bhhf;
    float iv = g[j]        + bih[j]        + bhh[j];
    float fv = g[j + 512]  + bih[j + 512]  + bhh[j + 512];
    float gv = g[j + 1024] + bih[j + 1024] + bhh[j + 1024];
    float ov = g[j + 1536] + bih[j + 1536] + bhh[j + 1536];
    size_t idx = (size_t)dir * 524288 + (size_t)n * 512 + j;
    float cv = sigmoidf_(fv) * c[idx] + sigmoidf_(iv) * tanhf(gv);
    float hv = sigmoidf_(ov) * tanhf(cv);
    c[idx] = cv;
    h[idx] = hv;
    hbf[idx] = f2bf(hv);
}

__global__ __launch_bounds__(256) void k_feat(const float* __restrict__ h,
                                              float* __restrict__ feat,
                                              unsigned short* __restrict__ featbf) {
    int idx = blockIdx.x * 256 + threadIdx.x;
    int n = idx >> 10;
    int d = idx & 1023;
    float v = (d < 512) ? h[(size_t)n * 512 + d]
                        : h[524288 + (size_t)n * 512 + (d - 512)];
    feat[idx] = v;
    featbf[idx] = f2bf(v);
}

// ---------------- generic bf16 GEMM: C[M][N] = A[M][K] @ B[N][K]^T ----------------
__global__ __launch_bounds__(256) void k_gemm_bt(
    const unsigned short* __restrict__ A, int lda,
    const unsigned short* __restrict__ B, int ldb,
    float* __restrict__ C, int ldc, int K) {
    __shared__ unsigned short As[64][72];
    __shared__ unsigned short Bs[64][72];
    const int tid = threadIdx.x;
    const int m0 = blockIdx.x * 64;
    const int n0 = blockIdx.y * 64;
    const int lane = tid & 63;
    const int wvq = tid >> 6;
    const int wm = (wvq >> 1) * 32;
    const int wn = (wvq & 1) * 32;
    const int srow = tid >> 2;
    const int sk0 = (tid & 3) * 16;
    const int arow = lane & 15;
    const int kq = (lane >> 4) * 8;
    f32x4 acc[2][2];
#pragma unroll
    for (int i = 0; i < 2; ++i)
#pragma unroll
        for (int j = 0; j < 2; ++j) acc[i][j] = (f32x4){0.f, 0.f, 0.f, 0.f};
    const unsigned short* ar = A + (size_t)(m0 + srow) * lda;
    const unsigned short* br = B + (size_t)(n0 + srow) * ldb;
    for (int kb = 0; kb < K; kb += 64) {
        int k0 = kb + sk0;
        *(u16x8*)&As[srow][sk0]     = *(const u16x8*)&ar[k0];
        *(u16x8*)&As[srow][sk0 + 8] = *(const u16x8*)&ar[k0 + 8];
        *(u16x8*)&Bs[srow][sk0]     = *(const u16x8*)&br[k0];
        *(u16x8*)&Bs[srow][sk0 + 8] = *(const u16x8*)&br[k0 + 8];
        __syncthreads();
#pragma unroll
        for (int kk = 0; kk < 64; kk += 32) {
            bf16x8 af[2], bfg[2];
#pragma unroll
            for (int i = 0; i < 2; ++i) {
                af[i]  = *(const bf16x8*)&As[wm + i * 16 + arow][kk + kq];
                bfg[i] = *(const bf16x8*)&Bs[wn + i * 16 + arow][kk + kq];
            }
#pragma unroll
            for (int i = 0; i < 2; ++i)
#pragma unroll
                for (int j = 0; j < 2; ++j)
                    acc[i][j] = __builtin_amdgcn_mfma_f32_16x16x32_bf16(
                        af[i], bfg[j], acc[i][j], 0, 0, 0);
        }
        __syncthreads();
    }
    const int rrow = (lane >> 4) * 4;
    const int ccol = lane & 15;
#pragma unroll
    for (int i = 0; i < 2; ++i)
#pragma unroll
        for (int j = 0; j < 2; ++j) {
            int mr = m0 + wm + i * 16 + rrow;
            int nc = n0 + wn + j * 16 + ccol;
#pragma unroll
            for (int r = 0; r < 4; ++r)
                C[(size_t)(mr + r) * ldc + nc] = acc[i][j][r];
        }
}

// ---------------- Phase C: decoder building blocks ----------------

// 16-wave GRU block: out[m][c0+d] for d in [0,16), m in [0,16).
DEV void gru_block16(
    int c0,
    const float* __restrict__ aBase, long aStride,
    const float* __restrict__ addBase, long addStride,
    const float* __restrict__ hBase, long hStride,
    const unsigned short* __restrict__ W,
    const float* __restrict__ bih, const float* __restrict__ bhh,
    float* __restrict__ outBase, long outStride,
    int D, int K1, int K2,
    float (*sred)[3][16][17]) {
    const int tid = threadIdx.x;
    const int lane = tid & 63;
    const int wv = tid >> 6;          // 0..15
    const int p = lane & 15;
    const int kq = (lane >> 4) * 8;
    const int KW = K1 + K2;
    const int Kc = KW >> 4;           // per-wave K span
    const int kStart = wv * Kc;
    const bool hasAdd = (addBase != nullptr);

    f32x4 accA[3], accB[3];
#pragma unroll
    for (int g = 0; g < 3; ++g) {
        accA[g] = (f32x4){0.f, 0.f, 0.f, 0.f};
        accB[g] = (f32x4){0.f, 0.f, 0.f, 0.f};
    }
    const unsigned short* w0 = W + (size_t)(c0 + p) * KW;
    const unsigned short* w1 = w0 + (size_t)D * KW;
    const unsigned short* w2 = w1 + (size_t)D * KW;
    const float* aRow = aBase + (size_t)p * aStride;
    const float* addRow = hasAdd ? addBase + (size_t)p * addStride : (const float*)0;
    const float* hRow = hBase + (size_t)p * hStride;

    for (int k = kStart; k < kStart + Kc; k += 32) {
        const int kk = k + kq;
        f32x4 x0, x1;
        const bool inA = (k < K1);
        if (inA) {
            x0 = *(const f32x4*)&aRow[kk];
            x1 = *(const f32x4*)&aRow[kk + 4];
            if (hasAdd) {
                f32x4 y0 = *(const f32x4*)&addRow[kk];
                f32x4 y1 = *(const f32x4*)&addRow[kk + 4];
                x0 = x0 + y0; x1 = x1 + y1;
            }
        } else {
            x0 = *(const f32x4*)&hRow[kk - K1];
            x1 = *(const f32x4*)&hRow[kk - K1 + 4];
        }
        bf16x8 af = cvt8(x0, x1);
        bf16x8 b0 = *(const bf16x8*)&w0[kk];
        bf16x8 b1 = *(const bf16x8*)&w1[kk];
        bf16x8 b2 = *(const bf16x8*)&w2[kk];
        if (inA) {
            accA[0] = __builtin_amdgcn_mfma_f32_16x16x32_bf16(af, b0, accA[0], 0, 0, 0);
            accA[1] = __builtin_amdgcn_mfma_f32_16x16x32_bf16(af, b1, accA[1], 0, 0, 0);
            accA[2] = __builtin_amdgcn_mfma_f32_16x16x32_bf16(af, b2, accA[2], 0, 0, 0);
        } else {
            accB[0] = __builtin_amdgcn_mfma_f32_16x16x32_bf16(af, b0, accB[0], 0, 0, 0);
            accB[1] = __builtin_amdgcn_mfma_f32_16x16x32_bf16(af, b1, accB[1], 0, 0, 0);
            accB[2] = __builtin_amdgcn_mfma_f32_16x16x32_bf16(af, b2, accB[2], 0, 0, 0);
        }
    }

    const int mB = (lane >> 4) * 4;
    const int m = tid >> 4;
    const int d = tid & 15;

#pragma unroll
    for (int g = 0; g < 3; ++g)
#pragma unroll
        for (int r = 0; r < 4; ++r)
            sred[wv][g][mB + r][p] = accA[g][r];
    __syncthreads();
    float ir = 0.f, iz = 0.f, inn = 0.f;
    if (tid < 256) {
#pragma unroll
        for (int w = 0; w < 16; ++w) {
            ir += sred[w][0][m][d]; iz += sred[w][1][m][d]; inn += sred[w][2][m][d];
        }
    }
    __syncthreads();
#pragma unroll
    for (int g = 0; g < 3; ++g)
#pragma unroll
        for (int r = 0; r < 4; ++r)
            sred[wv][g][mB + r][p] = accB[g][r];
    __syncthreads();
    if (tid < 256) {
        float hr = 0.f, hz = 0.f, hn = 0.f;
#pragma unroll
        for (int w = 0; w < 16; ++w) {
            hr += sred[w][0][m][d]; hz += sred[w][1][m][d]; hn += sred[w][2][m][d];
        }
        int gd = c0 + d;
        float rg = sigmoidf_(ir + bih[gd] + hr + bhh[gd]);
        float zg = sigmoidf_(iz + bih[gd + D] + hz + bhh[gd + D]);
        float ng = tanhf(inn + bih[gd + 2 * D] + rg * (hn + bhh[gd + 2 * D]));
        float hp = hBase[(size_t)m * hStride + gd];
        outBase[(size_t)m * outStride + gd] = (1.0f - zg) * ng + zg * hp;
    }
}

// attention block (1024 thr): scores over hist[0..i] for batch b, softmax, ctx.
DEV void attn_block(int b, int i, const float* __restrict__ q_all,
                    const float* __restrict__ hist, float* __restrict__ ctxout,
                    float* __restrict__ satt) {
    const int tid = threadIdx.x;
    const int lane = tid & 63;
    const int wv = tid >> 6;
    const float* qb = q_all + ((size_t)b * 64 + i) * 1024;
    for (int t = wv; t <= i; t += 16) {
        const float* hrow = hist + ((size_t)t * 16 + b) * 1024;
        float s = 0.f;
        for (int dd = lane; dd < 1024; dd += 64) s += qb[dd] * hrow[dd];
        for (int o = 32; o > 0; o >>= 1) s += __shfl_down(s, o);
        if (lane == 0) satt[t] = s;
    }
    __syncthreads();
    if (wv == 0) {
        float v = (lane <= i) ? satt[lane] : -3.0e38f;
        float mx = v;
        for (int o = 32; o > 0; o >>= 1) mx = fmaxf(mx, __shfl_xor(mx, o));
        float e = (lane <= i) ? __expf(v - mx) : 0.f;
        float sum = e;
        for (int o = 32; o > 0; o >>= 1) sum += __shfl_xor(sum, o);
        if (lane <= i) satt[lane] = e / sum;
    }
    __syncthreads();
    const int dd = tid;
    float s = 0.f;
    for (int t = 0; t <= i; ++t)
        s += satt[t] * hist[((size_t)t * 16 + b) * 1024 + dd];
    ctxout[(size_t)b * 1024 + dd] = s;
}

// Launch A: blocks [0,64) gg-GRU, [64,80) attention, [80,112) eg-GRU of step i-1.
__global__ __launch_bounds__(1024) void k_dec_A(
    const float* __restrict__ feat, const float* __restrict__ q_all,
    float* __restrict__ hist, const float* __restrict__ psel,
    const unsigned short* __restrict__ ggW,
    const float* __restrict__ gg_bih, const float* __restrict__ gg_bhh,
    float* __restrict__ ctxb,
    const float* __restrict__ pn_prev, const float* __restrict__ e_prev,
    float* __restrict__ es_prev_out,
    const unsigned short* __restrict__ egW,
    const float* __restrict__ eg_bih, const float* __restrict__ eg_bhh,
    int i) {
    __shared__ float sred[16][3][16][17];
    __shared__ float satt[80];
    const int blk = blockIdx.x;
    if (blk < 64) {
        if (i >= 64) return;
        gru_block16(blk * 16, feat + (size_t)i * 1024, 65536L, psel, 1024L,
                    hist + (size_t)i * 16384, 1024L, ggW, gg_bih, gg_bhh,
                    hist + (size_t)(i + 1) * 16384, 1024L, 1024, 1024, 1024, sred);
    } else if (blk < 80) {
        if (i >= 64) return;
        attn_block(blk - 64, i, q_all, hist, ctxb, satt);
    } else {
        if (i < 1) return;
        gru_block16((blk - 80) * 16, pn_prev, 1024L, (const float*)0, 0L,
                    e_prev, 512L, egW, eg_bih, eg_bhh,
                    es_prev_out, 512L, 512, 1024, 512, sred);
    }
}

// Launch B: pg-GRU (64 blocks).
__global__ __launch_bounds__(1024) void k_dec_B(
    const float* __restrict__ feat, const float* __restrict__ ctxb,
    const float* __restrict__ psel,
    const unsigned short* __restrict__ pgW,
    const float* __restrict__ pg_bih, const float* __restrict__ pg_bhh,
    float* __restrict__ pn, int i) {
    __shared__ float sred[16][3][16][17];
    gru_block16(blockIdx.x * 16, feat + (size_t)i * 1024, 65536L, ctxb, 1024L,
                psel, 1024L, pgW, pg_bih, pg_bhh, pn, 1024L, 1024, 1024, 1024, sred);
}

__global__ __launch_bounds__(256) void k_cls(const float* __restrict__ es,
                                             const float* __restrict__ W,
                                             const float* __restrict__ bias,
                                             float* __restrict__ out) {
    int blk = blockIdx.x;
    int b = blk >> 6;
    int u = blk & 63;
    const float* erow = es + ((size_t)u * 16 + b) * 512;
    int tid = threadIdx.x;
    int lane = tid & 63;
    int wv = tid >> 6;
    for (int c = wv; c < 7; c += 4) {
        float s = 0.f;
        for (int k = lane; k < 512; k += 64) s += erow[k] * W[(size_t)c * 512 + k];
        for (int o = 32; o > 0; o >>= 1) s += __shfl_down(s, o);
        if (lane == 0) out[((size_t)b * 64 + u) * 7 + c] = s + bias[c];
    }
}

// ---------------- host ----------------

extern "C" void kernel_launch(void* const* d_in, const int* in_sizes, int n_in,
                              void* d_out, int out_size, void* d_ws, size_t ws_size,
                              hipStream_t stream) {
    (void)in_sizes; (void)n_in; (void)out_size; (void)ws_size;
    const float* x          = (const float*)d_in[0];
    const float* lstm_Wih_f = (const float*)d_in[1];
    const float* lstm_Whh_f = (const float*)d_in[2];
    const float* lstm_bih_f = (const float*)d_in[3];
    const float* lstm_bhh_f = (const float*)d_in[4];
    const float* lstm_Wih_b = (const float*)d_in[5];
    const float* lstm_Whh_b = (const float*)d_in[6];
    const float* lstm_bih_b = (const float*)d_in[7];
    const float* lstm_bhh_b = (const float*)d_in[8];
    const float* gg_Wih = (const float*)d_in[9];
    const float* gg_Whh = (const float*)d_in[10];
    const float* gg_bih = (const float*)d_in[11];
    const float* gg_bhh = (const float*)d_in[12];
    const float* Wg     = (const float*)d_in[13];
    const float* pg_Wih = (const float*)d_in[14];
    const float* pg_Whh = (const float*)d_in[15];
    const float* pg_bih = (const float*)d_in[16];
    const float* pg_bhh = (const float*)d_in[17];
    const float* eg_Wih = (const float*)d_in[18];
    const float* eg_Whh = (const float*)d_in[19];
    const float* eg_bih = (const float*)d_in[20];
    const float* eg_bhh = (const float*)d_in[21];
    const float* cls_W  = (const float*)d_in[22];
    const float* cls_b  = (const float*)d_in[23];

    char* wsp = (char*)d_ws;
    size_t off = 0;
    auto alloc = [&](size_t bytes) -> void* {
        void* p = wsp + off;
        off += (bytes + 255) & ~(size_t)255;
        return p;
    };
    unsigned short* xpad = (unsigned short*)alloc((size_t)20971520 * 2);       // 41.94 MB
    unsigned short* wcat = (unsigned short*)alloc((size_t)2 * 2048 * 832 * 2);
    unsigned short* hbf  = (unsigned short*)alloc((size_t)2 * 1024 * 512 * 2);
    float* hbuf  = (float*)alloc((size_t)2 * 1024 * 512 * 4);
    float* cbuf  = (float*)alloc((size_t)2 * 1024 * 512 * 4);
    float* gates = (float*)alloc((size_t)2 * 1024 * 2048 * 4);
    float* feat  = (float*)alloc((size_t)1024 * 1024 * 4);
    unsigned short* featbf = (unsigned short*)alloc((size_t)1024 * 1024 * 2);
    float* hist  = (float*)alloc((size_t)65 * 16 * 1024 * 4);
    float* q_all = (float*)alloc((size_t)1024 * 1024 * 4);
    float* ctxb  = (float*)alloc((size_t)16 * 1024 * 4);
    float* pnew  = (float*)alloc((size_t)64 * 16 * 1024 * 4);
    float* esb   = (float*)alloc((size_t)64 * 16 * 512 * 4);
    float* zeroD = (float*)alloc((size_t)16 * 1024 * 4);
    float* zeroH = (float*)alloc((size_t)16 * 512 * 4);
    unsigned short* WgTb = (unsigned short*)alloc((size_t)1024 * 1024 * 2);
    // Aliased decoder weight buffers (gates / xpad are dead after LSTM phase):
    unsigned short* ggWb = (unsigned short*)gates;                        // 12.58 MB < 16.78 MB
    unsigned short* pgWb = (unsigned short*)xpad;                         // 12.58 MB
    unsigned short* egWb = (unsigned short*)((char*)xpad + 12582912);     // +4.72 MB < 41.9 MB

    hipMemsetAsync(hbf, 0, (size_t)2 * 1024 * 512 * 2, stream);
    hipMemsetAsync(cbuf, 0, (size_t)2 * 1024 * 512 * 4, stream);
    hipMemsetAsync(hist, 0, (size_t)65 * 16 * 1024 * 4, stream);
    hipMemsetAsync(zeroD, 0, (size_t)16 * 1024 * 4, stream);
    hipMemsetAsync(zeroH, 0, (size_t)16 * 512 * 4, stream);

    k_build_xpad<<<81920, 256, 0, stream>>>(x, xpad);
    k_build_wcat<<<13312, 256, 0, stream>>>(lstm_Wih_f, lstm_Whh_f, lstm_Wih_b, lstm_Whh_b, wcat);

    for (int t = 0; t < 32; ++t) {
        k_lstm_gemm<<<dim3(32, 32), 256, 0, stream>>>(xpad, hbf, wcat, gates, t);
        k_lstm_point<<<4096, 256, 0, stream>>>(gates, cbuf, hbuf, hbf,
                                               lstm_bih_f, lstm_bhh_f, lstm_bih_b, lstm_bhh_b);
    }
    k_feat<<<4096, 256, 0, stream>>>(hbuf, feat, featbf);

    // decoder weight packing (after LSTM: reuses gates / xpad memory)
    k_cat_w<<<3072, 256, 0, stream>>>(gg_Wih, gg_Whh, ggWb, 1024, 1024);
    k_cat_w<<<3072, 256, 0, stream>>>(pg_Wih, pg_Whh, pgWb, 1024, 1024);
    k_cat_w<<<1536, 256, 0, stream>>>(eg_Wih, eg_Whh, egWb, 1024, 512);
    k_transpose_bf<<<dim3(16, 16), 256, 0, stream>>>(Wg, WgTb);
    k_gemm_bt<<<dim3(16, 16), 256, 0, stream>>>(featbf, 1024, WgTb, 1024, q_all, 1024, 1024);

    float* p0 = zeroD;
    float* p1 = zeroD;
    for (int i = 0; i <= 64; ++i) {
        float* psel = (i & 1) ? p1 : p0;
        const float* pn_prev = (i >= 1) ? pnew + (size_t)(i - 1) * 16384 : (const float*)0;
        const float* e_prev  = (i >= 2) ? esb + (size_t)(i - 2) * 8192 : zeroH;
        float* es_prev_out   = (i >= 1) ? esb + (size_t)(i - 1) * 8192 : (float*)0;
        k_dec_A<<<112, 1024, 0, stream>>>(feat, q_all, hist, psel,
                                          ggWb, gg_bih, gg_bhh, ctxb,
                                          pn_prev, e_prev, es_prev_out,
                                          egWb, eg_bih, eg_bhh, i);
        if (i < 64) {
            float* pn = pnew + (size_t)i * 16384;
            k_dec_B<<<64, 1024, 0, stream>>>(feat, ctxb, psel, pgWb, pg_bih, pg_bhh, pn, i);
            if (i & 1) p1 = pn; else p0 = pn;
        }
    }
    k_cls<<<1024, 256, 0, stream>>>(esb, cls_W, cls_b, (float*)d_out);
}